// Round 6
// baseline (1800.111 us; speedup 1.0000x reference)
//
#include <hip/hip_runtime.h>
#include <hip/hip_bf16.h>
#include <cstdint>
#include <cstddef>

#define BN 8192
#define MTOT 32768   // 4*BN

using bf16 = __hip_bfloat16;
typedef float f32x4 __attribute__((ext_vector_type(4)));
typedef short short8 __attribute__((ext_vector_type(8)));

__device__ __forceinline__ bf16 f2b(float v) { return __float2bfloat16(v); }
__device__ __forceinline__ float b2f(bf16 v) { return __bfloat162float(v); }
// sin(x)+cos(x) = sqrt(2)*sin(x+pi/4)
__device__ __forceinline__ float sincos_sum(float x) {
    return 1.41421356237f * __sinf(x + 0.78539816340f);
}

// Layouts are POSITION-MAJOR: k = pi*68 + ic, n = po*68 + oc.

// ---------------- Z0 prep (ws=5 only now), LDS-staged, one block per b ----------
__global__ __launch_bounds__(256)
void zprep_block(const float* __restrict__ xF, const float* __restrict__ cell,
                 const float* __restrict__ isc, bf16* __restrict__ Z,
                 int m0g, int CM)
{
    constexpr int KD = 1728, KTRUE = 1700;
    const int b = blockIdx.x, tid = threadIdx.x;
    __shared__ float s[68][37];   // stride 37 words (mod 32 = 5) -> conflict-free

    for (int i = tid; i < 64 * 36; i += 256) {
        int ic = i / 36, off = i % 36;
        s[ic][off] = sincos_sum(xF[((size_t)b * 64 + ic) * 36 + off]);
    }
    if (tid < 2) {
        float t = sincos_sum(cell[b * 2 + tid]);
        #pragma unroll
        for (int off = 0; off < 36; off++) s[64 + tid][off] = t;
    }
    if (tid >= 64 && tid < 136) {
        int j = tid - 64;
        int ic = j / 36, off = j % 36;
        s[66 + ic][off] = sincos_sum(isc[((size_t)b * 2 + ic) * 36 + off]);
    }
    __syncthreads();

    // vectorized: 8 consecutive k per thread -> short8 store (16B, coalesced)
    for (int i = tid; i < 4 * (KD / 8); i += 256) {
        int q = i / (KD / 8), j8 = i % (KD / 8);
        int gm = q * BN + b;
        if (gm < m0g || gm >= m0g + CM) continue;
        int kbase = j8 * 8;
        short8 pack;
        #pragma unroll
        for (int u = 0; u < 8; u++) {
            int k = kbase + u;
            float v = 0.f;
            if (k < KTRUE) {
                int pi = k / 68, ic = k % 68;
                int r = (q >> 1) + pi / 5;       // (6-WS)=1
                int c = (q & 1) + pi % 5;
                v = s[ic][r * 6 + c];
            }
            bf16 bv = f2b(v);
            pack[u] = *reinterpret_cast<short*>(&bv);
        }
        *reinterpret_cast<short8*>(&Z[(size_t)(gm - m0g) * KD + kbase]) = pack;
    }
}

// ---------------- megabuild: all weights/bias/const-cols in ONE kernel -----------
template<int WSv>
__device__ __forceinline__ bf16 conv_elem(const float* __restrict__ src, int n, int k)
{
    constexpr int KTRUE = 68 * WSv * WSv;
    float v = 0.f;
    if (n < KTRUE && k < KTRUE) {
        int po = n / 68, oc = n % 68, ro = po / WSv, co = po % WSv;
        int pi = k / 68, ic = k % 68, ri = pi / WSv, ci = pi % WSv;
        int kr = ri - ro + 1, kc = ci - co + 1;
        if (kr >= 0 && kr < 3 && kc >= 0 && kc < 3)
            v = src[((oc * 68 + ic) * 3 + kr) * 3 + kc];
    }
    return f2b(v);
}
template<int WSv>
__device__ __forceinline__ bf16 lin_elem(const float* __restrict__ wl, int n, int k)
{
    constexpr int KTRUE = 68 * WSv * WSv;
    float v = 0.f;
    if (n < 576 && k < KTRUE) {
        int pi = k / 68, ic = k % 68;
        v = wl[(size_t)n * KTRUE + ic * (WSv * WSv) + pi];  // ref k-order = ic*ws^2+pi
    }
    return f2b(v);
}

__global__ void megabuild(const float* __restrict__ c1w, const float* __restrict__ c3w,
                          const float* __restrict__ l5w, const float* __restrict__ l4w,
                          const float* __restrict__ l3w, const float* __restrict__ fw,
                          const float* __restrict__ c1b, const float* __restrict__ c3b,
                          const float* __restrict__ bl5, const float* __restrict__ bl4,
                          const float* __restrict__ bl3, const float* __restrict__ bfin,
                          const float* __restrict__ cell, const float* __restrict__ isc,
                          bf16* __restrict__ w1d5, bf16* __restrict__ w3d5,
                          bf16* __restrict__ w1d4, bf16* __restrict__ w3d4,
                          bf16* __restrict__ w1d3, bf16* __restrict__ w3d3,
                          bf16* __restrict__ wl5p, bf16* __restrict__ wl4p,
                          bf16* __restrict__ wl3p, bf16* __restrict__ wfp,
                          float* __restrict__ bias,
                          bf16* __restrict__ Z4, bf16* __restrict__ Z3)
{
    constexpr unsigned S0 = 2u*1792*1728, S1 = 2u*1152*1088, S2 = 2u*640*640;
    constexpr unsigned S3 = 640u*1728, S4 = 640u*1088, S5 = 640u*640;
    constexpr unsigned S6 = 128u*576, S7 = 9216;
    constexpr unsigned S8 = 4u*8192*16*4, S9 = 4u*8192*9*4, S10 = 32768u*28;
    constexpr unsigned O1=S0, O2=O1+S1, O3=O2+S2, O4=O3+S3, O5=O4+S4, O6=O5+S5,
                       O7=O6+S6, O8=O7+S7, O9=O8+S8, O10=O9+S9, OT=O10+S10;
    unsigned e = blockIdx.x * 256u + threadIdx.x;
    if (e >= OT) return;
    if (e < O1) {
        constexpr unsigned per = 1792u*1728;
        unsigned i = (e < per) ? e : e - per;
        bf16* dst = (e < per) ? w1d5 : w3d5;
        const float* src = (e < per) ? c1w : c3w;
        dst[i] = conv_elem<5>(src, (int)(i / 1728u), (int)(i % 1728u));
    } else if (e < O2) {
        unsigned i0 = e - O1; constexpr unsigned per = 1152u*1088;
        unsigned i = (i0 < per) ? i0 : i0 - per;
        bf16* dst = (i0 < per) ? w1d4 : w3d4;
        const float* src = (i0 < per) ? c1w : c3w;
        dst[i] = conv_elem<4>(src, (int)(i / 1088u), (int)(i % 1088u));
    } else if (e < O3) {
        unsigned i0 = e - O2; constexpr unsigned per = 640u*640;
        unsigned i = (i0 < per) ? i0 : i0 - per;
        bf16* dst = (i0 < per) ? w1d3 : w3d3;
        const float* src = (i0 < per) ? c1w : c3w;
        dst[i] = conv_elem<3>(src, (int)(i / 640u), (int)(i % 640u));
    } else if (e < O4) {
        unsigned i = e - O3;
        wl5p[i] = lin_elem<5>(l5w, (int)(i / 1728u), (int)(i % 1728u));
    } else if (e < O5) {
        unsigned i = e - O4;
        wl4p[i] = lin_elem<4>(l4w, (int)(i / 1088u), (int)(i % 1088u));
    } else if (e < O6) {
        unsigned i = e - O5;
        wl3p[i] = lin_elem<3>(l3w, (int)(i / 640u), (int)(i % 640u));
    } else if (e < O7) {
        unsigned i = e - O6, n = i / 576u, k = i % 576u;
        wfp[i] = (n < 64u) ? f2b(fw[n * 576u + k]) : f2b(0.f);
    } else if (e < O8) {
        int i = (int)(e - O7);
        float v = 0.f;
        if (i < 1792)      { int n = i;        if (n < 1700) v = c1b[n % 68]; }
        else if (i < 3584) { int n = i - 1792; if (n < 1700) v = c3b[n % 68]; }
        else if (i < 4736) { int n = i - 3584; if (n < 1088) v = c1b[n % 68]; }
        else if (i < 5888) { int n = i - 4736; if (n < 1088) v = c3b[n % 68]; }
        else if (i < 6528) { int n = i - 5888; if (n < 612)  v = c1b[n % 68]; }
        else if (i < 7168) { int n = i - 6528; if (n < 612)  v = c3b[n % 68]; }
        else if (i < 7808) { int n = i - 7168; if (n < 576)  v = bl5[n]; }
        else if (i < 8448) { int n = i - 7808; if (n < 576)  v = bl4[n]; }
        else if (i < 9088) { int n = i - 8448; if (n < 576)  v = bl3[n]; }
        else               { int n = i - 9088; if (n < 64)   v = bfin[n]; }
        bias[i] = v;
    } else if (e < O9) {
        // Z4 const cols (cell/isc), ic = 64..67
        unsigned i = e - O8;
        int j = (int)(i & 3u); i >>= 2;
        int pi = (int)(i & 15u); i >>= 4;
        int b = (int)(i & 8191u); int q = (int)(i >> 13);
        float t;
        if (j < 2) t = cell[b * 2 + j];
        else {
            int r = (q >> 1) * 2 + pi / 4, c = (q & 1) * 2 + pi % 4;
            t = isc[((size_t)b * 2 + (j - 2)) * 36 + r * 6 + c];
        }
        Z4[((size_t)q * BN + b) * 1088 + pi * 68 + 64 + j] = f2b(sincos_sum(t));
    } else if (e < O10) {
        // Z3 const cols
        unsigned i = e - O9;
        int j = (int)(i & 3u); i >>= 2;
        int pi = (int)(i % 9u); i /= 9u;
        int b = (int)(i & 8191u); int q = (int)(i >> 13);
        float t;
        if (j < 2) t = cell[b * 2 + j];
        else {
            int r = (q >> 1) * 3 + pi / 3, c = (q & 1) * 3 + pi % 3;
            t = isc[((size_t)b * 2 + (j - 2)) * 36 + r * 6 + c];
        }
        Z3[((size_t)q * BN + b) * 640 + pi * 68 + 64 + j] = f2b(sincos_sum(t));
    } else {
        // Z3 pad cols 612..639 = 0 (avoid NaN-poison from workspace)
        unsigned i = e - O10;
        int m = (int)(i / 28u), t = (int)(i % 28u);
        Z3[(size_t)m * 640 + 612 + t] = f2b(0.f);
    }
}

// ---------------- async global->LDS, 16B per lane (m97 idiom) --------------------
__device__ __forceinline__ void gload_lds16(const bf16* g, const bf16* lds_wave_base)
{
    unsigned off = (unsigned)(uintptr_t)lds_wave_base;
    off = __builtin_amdgcn_readfirstlane(off);
    __builtin_amdgcn_global_load_lds((const __attribute__((address_space(1))) unsigned int*)g,
                                     (__attribute__((address_space(3))) unsigned int*)off,
                                     16, 0, 0);
}

__device__ __forceinline__ int imin(int a, int b) { return a < b ? a : b; }
__device__ __forceinline__ int imax(int a, int b) { return a > b ? a : b; }

// =============================================================================
// gemm9: LDS-traffic-minimized pipelined GEMM.
// Diagnosis (r5): all-LDS staging made the LDS data pipe the bottleneck
// (64KB frag reads + 24KB writes per block-iter ~ 1570+ cy >> 300 cy MFMA).
// Fix: A-fragments are row-major-along-K == the MFMA A register layout, so
// load them DIRECTLY global->VGPR (per-lane dwordx4: 16 rows x 64B, served by
// L1/L2/L3 on the TA pipe, overlapping LDS). Only B (weights, small, L2-hot,
// shared by 2 waves) stays LDS-staged, triple-buffered, swizzled (conflict-free,
// verified r3: SQ_LDS_BANK_CONFLICT=0).
// Block: 256 threads, 4 waves (2M x 2N), tile 128x128, BK=32. LDS 24 KiB; VGPR
// ~145 (__launch_bounds__(256,3)) -> 3 blocks/CU. A loaded one iter ahead into
// ping-pong register sets (all indices compile-time -> no scratch, rule #20).
// vmcnt ledger per iter t: issue 4 A-loads(t+1) + 2 B-stages(t+2) ->
//   vmcnt(6) = drain everything older, incl. B(t+1)'s 2 stages (issued t-1);
//   tail: no pfB -> vmcnt(4); none -> no wait. Compiler independently inserts
//   its own waits for the A registers (redundant but safe). s_barrier per iter
//   orders the B-buffer WAR (stage t+2 vs reads t-1, 2 barriers apart).
// Persistent grid 768 (3/CU), XCD-affine m-partition (r5 structure).
// EPI: 0 bias+relu+sincos->C ; 1 bias+relu->C ;
//      2 bias+relu+sincos -> scatter into Z_next (window WN)
// =============================================================================
template<int EPI, int WS, int WN>
__global__ __launch_bounds__(256, 3)
void gemm9(const bf16* __restrict__ A, const bf16* __restrict__ Bm, int KD,
           const float* __restrict__ bias, int ntiles, int mtiles,
           bf16* __restrict__ C, int ldc, int nlimit,
           int m0g, bf16* __restrict__ znext)
{
    __shared__ bf16 Bs[3][4096];    // 3 bufs x 128 rows x 32 cols = 24 KiB
    const int tid = threadIdx.x;
    const int wave = tid >> 6, lane = tid & 63;
    const int l15 = lane & 15, lq = lane >> 4;
    const int wr = (wave >> 1) * 64, wc = (wave & 1) * 64;

    const int xcd = blockIdx.x & 7, lblk = blockIdx.x >> 3;
    const int bpx = (int)gridDim.x >> 3;         // blocks per XCD
    const int mloc = mtiles >> 3;                // m-tiles per XCD (mtiles%8==0)
    const int tot = mloc * ntiles;

    // B staging map: 256 thr x 16B = 4KB/call; 2 calls cover 128 rows.
    // row = tid>>2 (0..63), colgrp = tid&3; src colgrp ^= (row>>1)&3.
    // Row +64 has identical XOR (64 = 0 mod 8).
    const int srow = tid >> 2;
    const int scx = (tid & 3) ^ ((srow >> 1) & 3);
    const int sOff = srow * 32 + (tid & 3) * 8;
    // B frag read: row = wc + j*16 + l15 (16-aligned base) -> XOR = (l15>>1)&3
    const int swz = (lq ^ ((l15 >> 1) & 3)) * 8;
    const int offB0 = (wc + l15) * 32 + swz;     // + j*512

    for (int w = lblk; w < tot; w += bpx) {
        const int m_idx = (w / ntiles) * 8 + xcd;
        const int n_idx = w % ntiles;
        const int n0 = n_idx * 128, m0 = m_idx * 128;

        // ---- K-banding spans (32-aligned), BN=128 rules (proven r3-r5) ----
        int s0b = 0, s0e = KD, s1b = 0, s1e = 0, s2b = 0, s2e = 0;
        if (WS > 0) {
            int po_lo = imin(n0 / 68, WS * WS - 1);
            int po_hi = imin((n0 + 127) / 68, WS * WS - 1);
            int ro_lo = po_lo / WS, ro_hi = po_hi / WS;
            int r_lo = imax(ro_lo - 1, 0), r_hi = imin(ro_hi + 1, WS - 1);
            int ci_lo = 0, ci_hi = WS - 1;
            if (ro_lo == ro_hi) {
                ci_lo = imax(po_lo % WS - 1, 0);
                ci_hi = imin(po_hi % WS + 1, WS - 1);
            }
            if (ci_lo == 0 && ci_hi == WS - 1) {
                s0b = (r_lo * WS * 68) & ~31;
                s0e = imin(KD, ((r_hi + 1) * WS * 68 + 31) & ~31);
            } else {
                s0b = ((r_lo * WS + ci_lo) * 68) & ~31;
                s0e = imin(KD, (((r_lo * WS + ci_hi + 1) * 68) + 31) & ~31);
                if (r_hi > r_lo) {
                    s1b = (((r_lo + 1) * WS + ci_lo) * 68) & ~31;
                    s1e = imin(KD, ((((r_lo + 1) * WS + ci_hi + 1) * 68) + 31) & ~31);
                }
                if (r_hi > r_lo + 1) {
                    s2b = (((r_lo + 2) * WS + ci_lo) * 68) & ~31;
                    s2e = imin(KD, ((((r_lo + 2) * WS + ci_hi + 1) * 68) + 31) & ~31);
                }
            }
        }
        const int c0 = (s0e - s0b) >> 5;
        const int c1 = c0 + ((s1e - s1b) >> 5);
        const int nt = c1 + ((s2e - s2b) >> 5);
        auto k0_of = [&](int t2) -> int {
            int k = s0b + (t2 << 5);
            if (t2 >= c0) k = s1b + ((t2 - c0) << 5);
            if (t2 >= c1) k = s2b + ((t2 - c1) << 5);
            return k;
        };

        const bf16* bSrc = Bm + (size_t)(n0 + srow) * KD + scx * 8;
        auto stageB = [&](int k0, int buf) {     // 2 loads per stage
            gload_lds16(bSrc + k0, &Bs[buf][sOff]);
            gload_lds16(bSrc + k0 + (size_t)64 * KD, &Bs[buf][sOff + 2048]);
        };

        // per-lane A fragment pointers (direct global->reg; layout == MFMA A)
        const bf16* aR0 = A + (size_t)(m0 + wr +  0 + l15) * KD + lq * 8;
        const bf16* aR1 = A + (size_t)(m0 + wr + 16 + l15) * KD + lq * 8;
        const bf16* aR2 = A + (size_t)(m0 + wr + 32 + l15) * KD + lq * 8;
        const bf16* aR3 = A + (size_t)(m0 + wr + 48 + l15) * KD + lq * 8;

        f32x4 acc[4][4];
        #pragma unroll
        for (int i = 0; i < 4; i++)
            #pragma unroll
            for (int j = 0; j < 4; j++) { f32x4 z = {0.f, 0.f, 0.f, 0.f}; acc[i][j] = z; }

        short8 afC[4], afN[4];
        // ---- prologue: A(0) to regs; stage B(0),B(1); full drain ----
        {
            const int k0a = k0_of(0);
            afC[0] = *(const short8*)(aR0 + k0a);
            afC[1] = *(const short8*)(aR1 + k0a);
            afC[2] = *(const short8*)(aR2 + k0a);
            afC[3] = *(const short8*)(aR3 + k0a);
            stageB(k0a, 0);
            if (nt > 1) stageB(k0_of(1), 1);
            __syncthreads();
        }

        // ---- main loop ----
        for (int t = 0; t < nt; ++t) {
            const int cur = t % 3;
            const int nx = (t + 2) % 3;
            const bool pfA = (t + 1) < nt;
            const bool pfB = (t + 2) < nt;

            short8 bg[4];
            #pragma unroll
            for (int j = 0; j < 4; j++) bg[j] = *(const short8*)&Bs[cur][offB0 + j * 512];

            if (pfA) {
                const int kA = k0_of(t + 1);
                afN[0] = *(const short8*)(aR0 + kA);
                afN[1] = *(const short8*)(aR1 + kA);
                afN[2] = *(const short8*)(aR2 + kA);
                afN[3] = *(const short8*)(aR3 + kA);
            }
            if (pfB) stageB(k0_of(t + 2), nx);

            __builtin_amdgcn_s_setprio(1);
            #pragma unroll
            for (int i = 0; i < 4; i++)
                #pragma unroll
                for (int j = 0; j < 4; j++)
                    acc[i][j] = __builtin_amdgcn_mfma_f32_16x16x32_bf16(afC[i], bg[j], acc[i][j], 0, 0, 0);
            __builtin_amdgcn_s_setprio(0);

            if (pfA) {
                #pragma unroll
                for (int i = 0; i < 4; i++) afC[i] = afN[i];
            }

            if (pfB)      asm volatile("s_waitcnt vmcnt(6)" ::: "memory");
            else if (pfA) asm volatile("s_waitcnt vmcnt(4)" ::: "memory");
            __builtin_amdgcn_s_barrier();
        }

        // ---- epilogue ----
        float bj[4];
        #pragma unroll
        for (int j = 0; j < 4; j++) bj[j] = bias[n0 + wc + j * 16 + l15];

        #pragma unroll
        for (int i = 0; i < 4; i++) {
            #pragma unroll
            for (int j = 0; j < 4; j++) {
                int n = n0 + wc + j * 16 + l15;
                #pragma unroll
                for (int r = 0; r < 4; r++) {
                    int m = m0 + wr + i * 16 + lq * 4 + r;
                    float v = acc[i][j][r];
                    if (EPI == 0) {
                        if (n < nlimit) {
                            v += bj[j]; v = fmaxf(v, 0.f); v = sincos_sum(v);
                            C[(size_t)m * ldc + n] = f2b(v);
                        }
                    } else if (EPI == 1) {
                        if (n < nlimit) {
                            v += bj[j]; v = fmaxf(v, 0.f);
                            C[(size_t)m * ldc + n] = f2b(v);
                        }
                    } else {
                        if (n < 576) {
                            v += bj[j]; v = fmaxf(v, 0.f);
                            bf16 tv = f2b(sincos_sum(v));
                            int gm = m0g + m;
                            int q = gm >> 13, b = gm & (BN - 1);
                            int ch = n / 9, p = n % 9;
                            int R = p / 3 + (q >> 1) * 3, Cc = p % 3 + (q & 1) * 3;
                            constexpr int OFF = 6 - WN;
                            constexpr int KDN = (WN == 4) ? 1088 : 640;
                            #pragma unroll
                            for (int qr = 0; qr < 2; qr++) {
                                int rr = R - OFF * qr;
                                if (rr < 0 || rr >= WN) continue;
                                #pragma unroll
                                for (int qc = 0; qc < 2; qc++) {
                                    int cc = Cc - OFF * qc;
                                    if (cc < 0 || cc >= WN) continue;
                                    int pi = rr * WN + cc;
                                    znext[((size_t)((qr * 2 + qc) * BN + b)) * KDN + pi * 68 + ch] = tv;
                                }
                            }
                        }
                    }
                }
            }
        }
    }
}

// ---------------- old 128x128 kernel (verified) — final tiny GEMM ---------------
template<int EPI, int WS, int WN>
__global__ __launch_bounds__(256)
void gemm_bt(const bf16* __restrict__ A, const bf16* __restrict__ Bm, int KD,
             const float* __restrict__ bias, int ntiles,
             bf16* __restrict__ C, int ldc, int nlimit,
             int m0g, bf16* __restrict__ znext,
             const bf16* __restrict__ afin_xc, float* __restrict__ outp)
{
    __shared__ bf16 As[128 * 32];
    __shared__ bf16 Bs[128 * 32];
    const int tid = threadIdx.x;
    const int wave = tid >> 6, lane = tid & 63;
    const int l15 = lane & 15, lq = lane >> 4;
    const int wr = (wave >> 1) * 64, wc = (wave & 1) * 64;

    const int id = blockIdx.x;
    const int mt8 = (int)gridDim.x / (ntiles * 8);   // m-tiles per XCD
    const int xcd = id & 7, local = id >> 3;
    const int m_idx = xcd * mt8 + local / ntiles;
    const int n_idx = local % ntiles;
    const int n0 = n_idx * 128, m0 = m_idx * 128;

    int nspans = 1, sbeg[4], send[4];
    sbeg[0] = 0; send[0] = KD;
    if (WS > 0) {
        int po_lo = imin(n0 / 68, WS * WS - 1);
        int po_hi = imin((n0 + 127) / 68, WS * WS - 1);
        int ro_lo = po_lo / WS, ro_hi = po_hi / WS;
        int r_lo = imax(ro_lo - 1, 0), r_hi = imin(ro_hi + 1, WS - 1);
        int ci_lo = 0, ci_hi = WS - 1;
        if (ro_lo == ro_hi) {
            ci_lo = imax(po_lo % WS - 1, 0);
            ci_hi = imin(po_hi % WS + 1, WS - 1);
        }
        if (ci_lo == 0 && ci_hi == WS - 1) {
            sbeg[0] = (r_lo * WS * 68) & ~31;
            send[0] = imin(KD, ((r_hi + 1) * WS * 68 + 31) & ~31);
        } else {
            nspans = 0;
            for (int ri = r_lo; ri <= r_hi; ri++) {
                sbeg[nspans] = ((ri * WS + ci_lo) * 68) & ~31;
                send[nspans] = imin(KD, (((ri * WS + ci_hi + 1) * 68) + 31) & ~31);
                nspans++;
            }
        }
    }

    float bj[4];
    #pragma unroll
    for (int j = 0; j < 4; j++) bj[j] = bias[n0 + wc + j * 16 + l15];

    const bf16* Ab = A + (size_t)m0 * KD;
    const bf16* Bb = Bm + (size_t)n0 * KD;
    const int srow = tid >> 2, scol = (tid & 3) * 8;
    const bf16* aG0 = Ab + (size_t)srow * KD + scol;
    const bf16* aG1 = Ab + (size_t)(srow + 64) * KD + scol;
    const bf16* bG0 = Bb + (size_t)srow * KD + scol;
    const bf16* bG1 = Bb + (size_t)(srow + 64) * KD + scol;
    const bf16* lA0 = &As[wave * 512];
    const bf16* lA1 = &As[2048 + wave * 512];
    const bf16* lB0 = &Bs[wave * 512];
    const bf16* lB1 = &Bs[2048 + wave * 512];

    f32x4 acc[4][4];
    #pragma unroll
    for (int i = 0; i < 4; i++)
        #pragma unroll
        for (int j = 0; j < 4; j++) { f32x4 z = {0.f, 0.f, 0.f, 0.f}; acc[i][j] = z; }

    for (int s = 0; s < nspans; s++) {
        for (int k0 = sbeg[s]; k0 < send[s]; k0 += 32) {
            gload_lds16(aG0 + k0, lA0);
            gload_lds16(aG1 + k0, lA1);
            gload_lds16(bG0 + k0, lB0);
            gload_lds16(bG1 + k0, lB1);
            __syncthreads();
            short8 af[4], bg[4];
            #pragma unroll
            for (int i = 0; i < 4; i++) af[i] = *(const short8*)&As[(wr + i * 16 + l15) * 32 + lq * 8];
            #pragma unroll
            for (int j = 0; j < 4; j++) bg[j] = *(const short8*)&Bs[(wc + j * 16 + l15) * 32 + lq * 8];
            #pragma unroll
            for (int i = 0; i < 4; i++)
                #pragma unroll
                for (int j = 0; j < 4; j++)
                    acc[i][j] = __builtin_amdgcn_mfma_f32_16x16x32_bf16(af[i], bg[j], acc[i][j], 0, 0, 0);
            __syncthreads();
        }
    }

    #pragma unroll
    for (int i = 0; i < 4; i++) {
        #pragma unroll
        for (int j = 0; j < 4; j++) {
            int n = n0 + wc + j * 16 + l15;
            #pragma unroll
            for (int r = 0; r < 4; r++) {
                int m = m0 + wr + i * 16 + lq * 4 + r;
                float v = acc[i][j][r];
                if (EPI == 0) {
                    if (n < nlimit) {
                        v += bj[j]; v = fmaxf(v, 0.f); v = sincos_sum(v);
                        C[(size_t)m * ldc + n] = f2b(v);
                    }
                } else if (EPI == 1) {
                    if (n < nlimit) {
                        v += bj[j]; v = fmaxf(v, 0.f);
                        C[(size_t)m * ldc + n] = f2b(v);
                    }
                } else if (EPI == 2) {
                    if (n < 576) {
                        v += bj[j]; v = fmaxf(v, 0.f);
                        bf16 t = f2b(sincos_sum(v));
                        int gm = m0g + m;
                        int q = gm >> 13, b = gm & (BN - 1);
                        int ch = n / 9, p = n % 9;
                        int R = p / 3 + (q >> 1) * 3, Cc = p % 3 + (q & 1) * 3;
                        constexpr int OFF = 6 - WN;
                        constexpr int KDN = (WN == 4) ? 1088 : 640;
                        #pragma unroll
                        for (int qr = 0; qr < 2; qr++) {
                            int rr = R - OFF * qr;
                            if (rr < 0 || rr >= WN) continue;
                            #pragma unroll
                            for (int qc = 0; qc < 2; qc++) {
                                int cc = Cc - OFF * qc;
                                if (cc < 0 || cc >= WN) continue;
                                int pi = rr * WN + cc;
                                znext[((size_t)((qr * 2 + qc) * BN + b)) * KDN + pi * 68 + ch] = t;
                            }
                        }
                    }
                } else {
                    if (n < 64) {
                        v += bj[j];
                        int gm = m0g + m;
                        int f = gm * 64 + n;        // c-flat == out-flat
                        int b2 = f >> 8, rem = f & 255;
                        int ch2 = rem >> 2, ii = (rem >> 1) & 1, jj = rem & 1;
                        int qq = ii * 2 + jj;
                        const int offt[4] = {8, 6, 2, 0};
                        float xc = b2f(afin_xc[((size_t)qq * BN + b2) * 576 + ch2 * 9 + offt[qq]]);
                        outp[f] = v * xc;
                    }
                }
            }
        }
    }
}

extern "C" void kernel_launch(void* const* d_in, const int* in_sizes, int n_in,
                              void* d_out, int out_size, void* d_ws, size_t ws_size,
                              hipStream_t stream)
{
    const float* x    = (const float*)d_in[0];
    const float* cell = (const float*)d_in[1];
    const float* isc  = (const float*)d_in[2];
    const float* c1w  = (const float*)d_in[3];
    const float* c1b  = (const float*)d_in[4];
    const float* c3w  = (const float*)d_in[5];
    const float* c3b  = (const float*)d_in[6];
    const float* l5w  = (const float*)d_in[7];
    const float* l5b  = (const float*)d_in[8];
    const float* l4w  = (const float*)d_in[9];
    const float* l4b  = (const float*)d_in[10];
    const float* l3w  = (const float*)d_in[11];
    const float* l3b  = (const float*)d_in[12];
    const float* fw   = (const float*)d_in[13];
    const float* fb   = (const float*)d_in[14];

    char* base = (char*)d_ws;
    size_t cur = 0;
    auto take = [&](size_t bytes) -> char* {
        char* r = base + cur; cur += (bytes + 255) & ~(size_t)255; return r;
    };

    const size_t Z4B = (size_t)MTOT * 1088 * 2;   // 71.3 MB
    const size_t Z3B = (size_t)MTOT * 640 * 2;    // 41.9 MB
    const size_t AFB = (size_t)MTOT * 576 * 2;    // 37.7 MB
    size_t wbytes = 2 * (1792ull * 1728 + 1152ull * 1088 + 640ull * 640) * 2
                  + (640ull * 1728 + 640ull * 1088 + 640ull * 640) * 2
                  + 128ull * 576 * 2 + 9216ull * 4 + 64 * 256;
    auto need = [&](int nc) -> size_t {
        return Z4B + Z3B + AFB + wbytes + 2 * ((size_t)(MTOT / nc) * 1728 * 2);
    };
    // gemm9 needs CM % 1024 == 0 (mtiles = CM/128, %8) -> all nchunk <= 16 OK
    int nchunk = (ws_size >= need(1)) ? 1 : (ws_size >= need(2)) ? 2
               : (ws_size >= need(4)) ? 4 : (ws_size >= need(8)) ? 8 : 16;

    bf16* Z4   = (bf16*)take(Z4B);
    bf16* Z3   = (bf16*)take(Z3B);
    bf16* afinb = (bf16*)take(AFB);
    bf16* w1d5 = (bf16*)take(1792ull * 1728 * 2);
    bf16* w3d5 = (bf16*)take(1792ull * 1728 * 2);
    bf16* w1d4 = (bf16*)take(1152ull * 1088 * 2);
    bf16* w3d4 = (bf16*)take(1152ull * 1088 * 2);
    bf16* w1d3 = (bf16*)take(640ull * 640 * 2);
    bf16* w3d3 = (bf16*)take(640ull * 640 * 2);
    bf16* wl5p = (bf16*)take(640ull * 1728 * 2);
    bf16* wl4p = (bf16*)take(640ull * 1088 * 2);
    bf16* wl3p = (bf16*)take(640ull * 640 * 2);
    bf16* wfp  = (bf16*)take(128ull * 576 * 2);
    float* biasb = (float*)take(9216ull * 4);
    int CM = MTOT / nchunk;
    int mt = CM / 128;                          // mtiles for gemm9 + final kernel
    bf16* Za = (bf16*)take((size_t)CM * 1728 * 2);
    bf16* Zb = (bf16*)take((size_t)CM * 1728 * 2);

    // -------- stage 0: all weight repacks, bias, Z4/Z3 const cols, Z3 pad --------
    {
        constexpr unsigned OT = 2u*1792*1728 + 2u*1152*1088 + 2u*640*640
                              + 640u*1728 + 640u*1088 + 640u*640 + 128u*576 + 9216
                              + 4u*8192*16*4 + 4u*8192*9*4 + 32768u*28;
        megabuild<<<(OT + 255) / 256, 256, 0, stream>>>(
            c1w, c3w, l5w, l4w, l3w, fw, c1b, c3b, l5b, l4b, l3b, fb, cell, isc,
            w1d5, w3d5, w1d4, w3d4, w1d3, w3d3, wl5p, wl4p, wl3p, wfp, biasb, Z4, Z3);
    }

    // -------- ws=5: zprep -> conv1 -> conv3 -> lin (scatter into Z4) -------------
    for (int c = 0; c < nchunk; c++) {
        int m0g = c * CM;
        zprep_block<<<BN, 256, 0, stream>>>(x, cell, isc, Za, m0g, CM);
        gemm9<0, 5, 0><<<768, 256, 0, stream>>>(Za, w1d5, 1728, biasb + 0, 14, mt,
                                                Zb, 1728, 1728, 0, nullptr);
        gemm9<1, 5, 0><<<768, 256, 0, stream>>>(Zb, w3d5, 1728, biasb + 1792, 14, mt,
                                                Za, 1728, 1728, 0, nullptr);
        gemm9<2, 0, 4><<<768, 256, 0, stream>>>(Za, wl5p, 1728, biasb + 7168, 5, mt,
                                                nullptr, 0, 0, m0g, Z4);
    }
    // -------- ws=4: conv1(Z4) -> conv3 -> lin (scatter into Z3) ------------------
    for (int c = 0; c < nchunk; c++) {
        int m0g = c * CM;
        gemm9<0, 4, 0><<<768, 256, 0, stream>>>(Z4 + (size_t)m0g * 1088, w1d4, 1088,
                                                biasb + 3584, 9, mt, Zb, 1088, 1088,
                                                0, nullptr);
        gemm9<1, 4, 0><<<768, 256, 0, stream>>>(Zb, w3d4, 1088, biasb + 4736, 9, mt,
                                                Za, 1088, 1088, 0, nullptr);
        gemm9<2, 0, 3><<<768, 256, 0, stream>>>(Za, wl4p, 1088, biasb + 7808, 5, mt,
                                                nullptr, 0, 0, m0g, Z3);
    }
    // -------- ws=3: conv1(Z3) -> conv3 -> lin (-> afinb, identity layout) --------
    for (int c = 0; c < nchunk; c++) {
        int m0g = c * CM;
        gemm9<0, 3, 0><<<768, 256, 0, stream>>>(Z3 + (size_t)m0g * 640, w1d3, 640,
                                                biasb + 5888, 5, mt, Zb, 640, 640,
                                                0, nullptr);
        gemm9<1, 3, 0><<<768, 256, 0, stream>>>(Zb, w3d3, 640, biasb + 6528, 5, mt,
                                                Za, 640, 640, 0, nullptr);
        gemm9<1, 0, 0><<<768, 256, 0, stream>>>(Za, wl3p, 640, biasb + 8448, 5, mt,
                                                afinb + (size_t)m0g * 576, 576, 576,
                                                0, nullptr);
    }
    // -------- final: (afinb @ Wf) * xc --------------------------------------------
    for (int c = 0; c < nchunk; c++) {
        int m0g = c * CM;
        gemm_bt<3, 0, 0><<<mt, 256, 0, stream>>>(afinb + (size_t)m0g * 576, wfp, 576,
                                                 biasb + 9088, 1, nullptr, 0, 0, m0g,
                                                 nullptr, afinb, (float*)d_out);
    }
}

// Round 7
// 1323.432 us; speedup vs baseline: 1.3602x; 1.3602x over previous
//
#include <hip/hip_runtime.h>
#include <hip/hip_bf16.h>
#include <cstdint>
#include <cstddef>

#define BN 8192
#define MTOT 32768   // 4*BN

using bf16 = __hip_bfloat16;
typedef float f32x4 __attribute__((ext_vector_type(4)));
typedef short short8 __attribute__((ext_vector_type(8)));

__device__ __forceinline__ bf16 f2b(float v) { return __float2bfloat16(v); }
__device__ __forceinline__ float b2f(bf16 v) { return __bfloat162float(v); }
// sin(x)+cos(x) = sqrt(2)*sin(x+pi/4)
__device__ __forceinline__ float sincos_sum(float x) {
    return 1.41421356237f * __sinf(x + 0.78539816340f);
}

// Layouts are POSITION-MAJOR: k = pi*68 + ic, n = po*68 + oc.

// ---------------- Z0 prep (ws=5 only now), LDS-staged, one block per b ----------
__global__ __launch_bounds__(256)
void zprep_block(const float* __restrict__ xF, const float* __restrict__ cell,
                 const float* __restrict__ isc, bf16* __restrict__ Z,
                 int m0g, int CM)
{
    constexpr int KD = 1728, KTRUE = 1700;
    const int b = blockIdx.x, tid = threadIdx.x;
    __shared__ float s[68][37];   // stride 37 words (mod 32 = 5) -> conflict-free

    for (int i = tid; i < 64 * 36; i += 256) {
        int ic = i / 36, off = i % 36;
        s[ic][off] = sincos_sum(xF[((size_t)b * 64 + ic) * 36 + off]);
    }
    if (tid < 2) {
        float t = sincos_sum(cell[b * 2 + tid]);
        #pragma unroll
        for (int off = 0; off < 36; off++) s[64 + tid][off] = t;
    }
    if (tid >= 64 && tid < 136) {
        int j = tid - 64;
        int ic = j / 36, off = j % 36;
        s[66 + ic][off] = sincos_sum(isc[((size_t)b * 2 + ic) * 36 + off]);
    }
    __syncthreads();

    // vectorized: 8 consecutive k per thread -> short8 store (16B, coalesced)
    for (int i = tid; i < 4 * (KD / 8); i += 256) {
        int q = i / (KD / 8), j8 = i % (KD / 8);
        int gm = q * BN + b;
        if (gm < m0g || gm >= m0g + CM) continue;
        int kbase = j8 * 8;
        short8 pack;
        #pragma unroll
        for (int u = 0; u < 8; u++) {
            int k = kbase + u;
            float v = 0.f;
            if (k < KTRUE) {
                int pi = k / 68, ic = k % 68;
                int r = (q >> 1) + pi / 5;       // (6-WS)=1
                int c = (q & 1) + pi % 5;
                v = s[ic][r * 6 + c];
            }
            bf16 bv = f2b(v);
            pack[u] = *reinterpret_cast<short*>(&bv);
        }
        *reinterpret_cast<short8*>(&Z[(size_t)(gm - m0g) * KD + kbase]) = pack;
    }
}

// ---------------- megabuild: all weights/bias/const-cols in ONE kernel -----------
template<int WSv>
__device__ __forceinline__ bf16 conv_elem(const float* __restrict__ src, int n, int k)
{
    constexpr int KTRUE = 68 * WSv * WSv;
    float v = 0.f;
    if (n < KTRUE && k < KTRUE) {
        int po = n / 68, oc = n % 68, ro = po / WSv, co = po % WSv;
        int pi = k / 68, ic = k % 68, ri = pi / WSv, ci = pi % WSv;
        int kr = ri - ro + 1, kc = ci - co + 1;
        if (kr >= 0 && kr < 3 && kc >= 0 && kc < 3)
            v = src[((oc * 68 + ic) * 3 + kr) * 3 + kc];
    }
    return f2b(v);
}
template<int WSv>
__device__ __forceinline__ bf16 lin_elem(const float* __restrict__ wl, int n, int k)
{
    constexpr int KTRUE = 68 * WSv * WSv;
    float v = 0.f;
    if (n < 576 && k < KTRUE) {
        int pi = k / 68, ic = k % 68;
        v = wl[(size_t)n * KTRUE + ic * (WSv * WSv) + pi];  // ref k-order = ic*ws^2+pi
    }
    return f2b(v);
}

__global__ void megabuild(const float* __restrict__ c1w, const float* __restrict__ c3w,
                          const float* __restrict__ l5w, const float* __restrict__ l4w,
                          const float* __restrict__ l3w, const float* __restrict__ fw,
                          const float* __restrict__ c1b, const float* __restrict__ c3b,
                          const float* __restrict__ bl5, const float* __restrict__ bl4,
                          const float* __restrict__ bl3, const float* __restrict__ bfin,
                          const float* __restrict__ cell, const float* __restrict__ isc,
                          bf16* __restrict__ w1d5, bf16* __restrict__ w3d5,
                          bf16* __restrict__ w1d4, bf16* __restrict__ w3d4,
                          bf16* __restrict__ w1d3, bf16* __restrict__ w3d3,
                          bf16* __restrict__ wl5p, bf16* __restrict__ wl4p,
                          bf16* __restrict__ wl3p, bf16* __restrict__ wfp,
                          float* __restrict__ bias,
                          bf16* __restrict__ Z4, bf16* __restrict__ Z3)
{
    constexpr unsigned S0 = 2u*1792*1728, S1 = 2u*1152*1088, S2 = 2u*640*640;
    constexpr unsigned S3 = 640u*1728, S4 = 640u*1088, S5 = 640u*640;
    constexpr unsigned S6 = 128u*576, S7 = 9216;
    constexpr unsigned S8 = 4u*8192*16*4, S9 = 4u*8192*9*4, S10 = 32768u*28;
    constexpr unsigned O1=S0, O2=O1+S1, O3=O2+S2, O4=O3+S3, O5=O4+S4, O6=O5+S5,
                       O7=O6+S6, O8=O7+S7, O9=O8+S8, O10=O9+S9, OT=O10+S10;
    unsigned e = blockIdx.x * 256u + threadIdx.x;
    if (e >= OT) return;
    if (e < O1) {
        constexpr unsigned per = 1792u*1728;
        unsigned i = (e < per) ? e : e - per;
        bf16* dst = (e < per) ? w1d5 : w3d5;
        const float* src = (e < per) ? c1w : c3w;
        dst[i] = conv_elem<5>(src, (int)(i / 1728u), (int)(i % 1728u));
    } else if (e < O2) {
        unsigned i0 = e - O1; constexpr unsigned per = 1152u*1088;
        unsigned i = (i0 < per) ? i0 : i0 - per;
        bf16* dst = (i0 < per) ? w1d4 : w3d4;
        const float* src = (i0 < per) ? c1w : c3w;
        dst[i] = conv_elem<4>(src, (int)(i / 1088u), (int)(i % 1088u));
    } else if (e < O3) {
        unsigned i0 = e - O2; constexpr unsigned per = 640u*640;
        unsigned i = (i0 < per) ? i0 : i0 - per;
        bf16* dst = (i0 < per) ? w1d3 : w3d3;
        const float* src = (i0 < per) ? c1w : c3w;
        dst[i] = conv_elem<3>(src, (int)(i / 640u), (int)(i % 640u));
    } else if (e < O4) {
        unsigned i = e - O3;
        wl5p[i] = lin_elem<5>(l5w, (int)(i / 1728u), (int)(i % 1728u));
    } else if (e < O5) {
        unsigned i = e - O4;
        wl4p[i] = lin_elem<4>(l4w, (int)(i / 1088u), (int)(i % 1088u));
    } else if (e < O6) {
        unsigned i = e - O5;
        wl3p[i] = lin_elem<3>(l3w, (int)(i / 640u), (int)(i % 640u));
    } else if (e < O7) {
        unsigned i = e - O6, n = i / 576u, k = i % 576u;
        wfp[i] = (n < 64u) ? f2b(fw[n * 576u + k]) : f2b(0.f);
    } else if (e < O8) {
        int i = (int)(e - O7);
        float v = 0.f;
        if (i < 1792)      { int n = i;        if (n < 1700) v = c1b[n % 68]; }
        else if (i < 3584) { int n = i - 1792; if (n < 1700) v = c3b[n % 68]; }
        else if (i < 4736) { int n = i - 3584; if (n < 1088) v = c1b[n % 68]; }
        else if (i < 5888) { int n = i - 4736; if (n < 1088) v = c3b[n % 68]; }
        else if (i < 6528) { int n = i - 5888; if (n < 612)  v = c1b[n % 68]; }
        else if (i < 7168) { int n = i - 6528; if (n < 612)  v = c3b[n % 68]; }
        else if (i < 7808) { int n = i - 7168; if (n < 576)  v = bl5[n]; }
        else if (i < 8448) { int n = i - 7808; if (n < 576)  v = bl4[n]; }
        else if (i < 9088) { int n = i - 8448; if (n < 576)  v = bl3[n]; }
        else               { int n = i - 9088; if (n < 64)   v = bfin[n]; }
        bias[i] = v;
    } else if (e < O9) {
        // Z4 const cols (cell/isc), ic = 64..67
        unsigned i = e - O8;
        int j = (int)(i & 3u); i >>= 2;
        int pi = (int)(i & 15u); i >>= 4;
        int b = (int)(i & 8191u); int q = (int)(i >> 13);
        float t;
        if (j < 2) t = cell[b * 2 + j];
        else {
            int r = (q >> 1) * 2 + pi / 4, c = (q & 1) * 2 + pi % 4;
            t = isc[((size_t)b * 2 + (j - 2)) * 36 + r * 6 + c];
        }
        Z4[((size_t)q * BN + b) * 1088 + pi * 68 + 64 + j] = f2b(sincos_sum(t));
    } else if (e < O10) {
        // Z3 const cols
        unsigned i = e - O9;
        int j = (int)(i & 3u); i >>= 2;
        int pi = (int)(i % 9u); i /= 9u;
        int b = (int)(i & 8191u); int q = (int)(i >> 13);
        float t;
        if (j < 2) t = cell[b * 2 + j];
        else {
            int r = (q >> 1) * 3 + pi / 3, c = (q & 1) * 3 + pi % 3;
            t = isc[((size_t)b * 2 + (j - 2)) * 36 + r * 6 + c];
        }
        Z3[((size_t)q * BN + b) * 640 + pi * 68 + 64 + j] = f2b(sincos_sum(t));
    } else {
        // Z3 pad cols 612..639 = 0 (avoid NaN-poison from workspace)
        unsigned i = e - O10;
        int m = (int)(i / 28u), t = (int)(i % 28u);
        Z3[(size_t)m * 640 + 612 + t] = f2b(0.f);
    }
}

// ---------------- async global->LDS, 16B per lane (m97 idiom) --------------------
__device__ __forceinline__ void gload_lds16(const bf16* g, const bf16* lds_wave_base)
{
    unsigned off = (unsigned)(uintptr_t)lds_wave_base;
    off = __builtin_amdgcn_readfirstlane(off);
    __builtin_amdgcn_global_load_lds((const __attribute__((address_space(1))) unsigned int*)g,
                                     (__attribute__((address_space(3))) unsigned int*)off,
                                     16, 0, 0);
}

__device__ __forceinline__ int imin(int a, int b) { return a < b ? a : b; }
__device__ __forceinline__ int imax(int a, int b) { return a > b ? a : b; }

// =============================================================================
// gemm8 (r5 structure + vectorized epilogue):
//   WIDE=0: BM=256, BN=128 ; WIDE=1: BM=128, BN=256 (conv5 pair).
// 8 waves, BK=32, triple-buffered LDS (72 KiB -> 2 blocks/CU), ONE barrier per
// K-tile, counted vmcnt(3), conflict-free XOR swizzle (SQ_LDS_BANK_CONFLICT=0,
// verified r3), setprio around MFMA, persistent grid 512 with XCD-affine
// m-partition (r5, verified).
// NEW (r7): EPI 0/1 epilogue no longer issues 2-byte scalar stores. Each wave
// dumps its activated 64x64 bf16 sub-tile into a private LDS slab (64 rows x
// 66-pad; readback banks (33r+4c)%32 all-distinct -> conflict-free), then
// stores short8 (16B/lane, 128B per 8 lanes). Slabs alias the staging buffers
// (loop is finished; final in-loop barrier makes that safe) and a trailing
// __syncthreads() orders slab reads vs the NEXT persistent tile's staging.
// EPI: 0 bias+relu+sincos->C ; 1 bias+relu->C ;
//      2 bias+relu+sincos -> scatter into Z_next (window WN)
// =============================================================================
template<int EPI, int WS, int WN, int WIDE>
__global__ __launch_bounds__(512, 4)
void gemm8(const bf16* __restrict__ A, const bf16* __restrict__ Bm, int KD,
           const float* __restrict__ bias, int ntiles, int mtiles,
           bf16* __restrict__ C, int ldc, int nlimit,
           int m0g, bf16* __restrict__ znext)
{
    constexpr int BMc = WIDE ? 128 : 256;
    constexpr int BNc = WIDE ? 256 : 128;
    constexpr int NWN = WIDE ? 4 : 2;            // waves along N
    __shared__ bf16 smem[36864];                 // 72 KiB: As 3 bufs + Bs 3 bufs
    bf16* const AsB = smem;                      // As[buf] = AsB + buf*BMc*32
    bf16* const BsB = smem + 3 * BMc * 32;       // Bs[buf] = BsB + buf*BNc*32
    const int tid = threadIdx.x;
    const int wave = tid >> 6, lane = tid & 63;
    const int l15 = lane & 15, lq = lane >> 4;
    const int wr = (wave / NWN) * 64, wc = (wave % NWN) * 64;

    const int xcd = blockIdx.x & 7, lblk = blockIdx.x >> 3;
    const int bpx = (int)gridDim.x >> 3;         // blocks per XCD
    const int mloc = mtiles >> 3;                // m-tiles per XCD (mtiles%8==0)
    const int tot = mloc * ntiles;

    // staging thread map: row = tid>>2, colgrp = tid&3; src colgrp ^= (row>>1)&3
    const int srow = tid >> 2;
    const int scx = (tid & 3) ^ ((srow >> 1) & 3);
    const int sOff = srow * 32 + (tid & 3) * 8;
    // fragment read swizzle: row = 16-aligned + l15 -> (row>>1)&3 = (l15>>1)&3
    const int swz = (lq ^ ((l15 >> 1) & 3)) * 8;
    const int offA0 = (wr + l15) * 32 + swz;     // + i*512
    const int offB0 = (wc + l15) * 32 + swz;     // + j*512

    for (int w = lblk; w < tot; w += bpx) {
        const int m_idx = (w / ntiles) * 8 + xcd;
        const int n_idx = w % ntiles;
        const int n0 = n_idx * BNc, m0 = m_idx * BMc;

        // ---- K-banding spans (32-aligned) ----
        int s0b = 0, s0e = KD, s1b = 0, s1e = 0, s2b = 0, s2e = 0;
        if (WS > 0) {
            int po_lo = imin(n0 / 68, WS * WS - 1);
            int po_hi = imin((n0 + BNc - 1) / 68, WS * WS - 1);
            int ro_lo = po_lo / WS, ro_hi = po_hi / WS;
            int r_lo = imax(ro_lo - 1, 0), r_hi = imin(ro_hi + 1, WS - 1);
            int ci_lo = 0, ci_hi = WS - 1;
            if (ro_lo == ro_hi) {
                ci_lo = imax(po_lo % WS - 1, 0);
                ci_hi = imin(po_hi % WS + 1, WS - 1);
            }
            if (ci_lo == 0 && ci_hi == WS - 1) {
                s0b = (r_lo * WS * 68) & ~31;
                s0e = imin(KD, ((r_hi + 1) * WS * 68 + 31) & ~31);
            } else {
                s0b = ((r_lo * WS + ci_lo) * 68) & ~31;
                s0e = imin(KD, (((r_lo * WS + ci_hi + 1) * 68) + 31) & ~31);
                if (r_hi > r_lo) {
                    s1b = (((r_lo + 1) * WS + ci_lo) * 68) & ~31;
                    s1e = imin(KD, ((((r_lo + 1) * WS + ci_hi + 1) * 68) + 31) & ~31);
                }
                if (r_hi > r_lo + 1) {
                    s2b = (((r_lo + 2) * WS + ci_lo) * 68) & ~31;
                    s2e = imin(KD, ((((r_lo + 2) * WS + ci_hi + 1) * 68) + 31) & ~31);
                }
            }
        }
        const int c0 = (s0e - s0b) >> 5;
        const int c1 = c0 + ((s1e - s1b) >> 5);
        const int nt = c1 + ((s2e - s2b) >> 5);
        auto k0_of = [&](int t2) -> int {
            int k = s0b + (t2 << 5);
            if (t2 >= c0) k = s1b + ((t2 - c0) << 5);
            if (t2 >= c1) k = s2b + ((t2 - c1) << 5);
            return k;
        };

        const bf16* aSrc = A + (size_t)(m0 + srow) * KD + scx * 8;
        const bf16* bSrc = Bm + (size_t)(n0 + srow) * KD + scx * 8;

        auto stageAll = [&](int k0, int buf) {   // 3 loads total
            if (WIDE) {
                gload_lds16(aSrc + k0, AsB + buf * (BMc * 32) + sOff);
                gload_lds16(bSrc + k0, BsB + buf * (BNc * 32) + sOff);
                gload_lds16(bSrc + k0 + (size_t)128 * KD, BsB + buf * (BNc * 32) + sOff + 4096);
            } else {
                gload_lds16(aSrc + k0, AsB + buf * (BMc * 32) + sOff);
                gload_lds16(aSrc + k0 + (size_t)128 * KD, AsB + buf * (BMc * 32) + sOff + 4096);
                gload_lds16(bSrc + k0, BsB + buf * (BNc * 32) + sOff);
            }
        };

        f32x4 acc[4][4];
        #pragma unroll
        for (int i = 0; i < 4; i++)
            #pragma unroll
            for (int j = 0; j < 4; j++) { f32x4 z = {0.f, 0.f, 0.f, 0.f}; acc[i][j] = z; }

        // ---- prologue: stage tiles 0,1; full drain ----
        {
            stageAll(k0_of(0), 0);
            if (nt > 1) stageAll(k0_of(1), 1);
            __syncthreads();
        }

        // ---- main loop ----
        for (int t = 0; t < nt; ++t) {
            const int cur = t % 3;
            const int nx = (t + 2) % 3;
            const bool pf = (t + 2) < nt;

            const bf16* Ac = AsB + cur * (BMc * 32);
            const bf16* Bc = BsB + cur * (BNc * 32);

            short8 af[4], bg[4];
            #pragma unroll
            for (int i = 0; i < 4; i++) af[i] = *(const short8*)&Ac[offA0 + i * 512];
            #pragma unroll
            for (int j = 0; j < 4; j++) bg[j] = *(const short8*)&Bc[offB0 + j * 512];

            if (pf) stageAll(k0_of(t + 2), nx);

            __builtin_amdgcn_s_setprio(1);
            #pragma unroll
            for (int i = 0; i < 4; i++)
                #pragma unroll
                for (int j = 0; j < 4; j++)
                    acc[i][j] = __builtin_amdgcn_mfma_f32_16x16x32_bf16(af[i], bg[j], acc[i][j], 0, 0, 0);
            __builtin_amdgcn_s_setprio(0);

            if (pf) asm volatile("s_waitcnt vmcnt(3)" ::: "memory");
            else    asm volatile("s_waitcnt vmcnt(0)" ::: "memory");
            __builtin_amdgcn_s_barrier();
        }

        // ---- epilogue ----
        float bj[4];
        #pragma unroll
        for (int j = 0; j < 4; j++) bj[j] = bias[n0 + wc + j * 16 + l15];

        if (EPI == 0 || EPI == 1) {
            // per-wave 64x66 LDS slab (aliases staging bufs; safe after final barrier)
            bf16* ep = smem + wave * 4224;
            #pragma unroll
            for (int i = 0; i < 4; i++) {
                #pragma unroll
                for (int j = 0; j < 4; j++) {
                    #pragma unroll
                    for (int r = 0; r < 4; r++) {
                        float v = acc[i][j][r] + bj[j];
                        v = fmaxf(v, 0.f);
                        if (EPI == 0) v = sincos_sum(v);
                        ep[(i * 16 + lq * 4 + r) * 66 + j * 16 + l15] = f2b(v);
                    }
                }
            }
            // readback: lane l -> row (l>>3)+8*rd, 16B at col (l&7)*8; conflict-free
            const int rr0 = lane >> 3, c8 = lane & 7;
            const int nbase = n0 + wc + c8 * 8;
            #pragma unroll
            for (int rd = 0; rd < 8; rd++) {
                int row = rd * 8 + rr0;
                short8 pack = *(const short8*)&ep[row * 66 + c8 * 8];
                if (nbase < nlimit)
                    *(short8*)&C[(size_t)(m0 + wr + row) * ldc + nbase] = pack;
            }
            __syncthreads();   // slab reads done before next tile's staging writes
        } else {
            #pragma unroll
            for (int i = 0; i < 4; i++) {
                #pragma unroll
                for (int j = 0; j < 4; j++) {
                    int n = n0 + wc + j * 16 + l15;
                    #pragma unroll
                    for (int r = 0; r < 4; r++) {
                        int m = m0 + wr + i * 16 + lq * 4 + r;
                        float v = acc[i][j][r];
                        if (n < 576) {
                            v += bj[j]; v = fmaxf(v, 0.f);
                            bf16 tv = f2b(sincos_sum(v));
                            int gm = m0g + m;
                            int q = gm >> 13, b = gm & (BN - 1);
                            int ch = n / 9, p = n % 9;
                            int R = p / 3 + (q >> 1) * 3, Cc = p % 3 + (q & 1) * 3;
                            constexpr int OFF = 6 - WN;
                            constexpr int KDN = (WN == 4) ? 1088 : 640;
                            #pragma unroll
                            for (int qr = 0; qr < 2; qr++) {
                                int rr = R - OFF * qr;
                                if (rr < 0 || rr >= WN) continue;
                                #pragma unroll
                                for (int qc = 0; qc < 2; qc++) {
                                    int cc = Cc - OFF * qc;
                                    if (cc < 0 || cc >= WN) continue;
                                    int pi = rr * WN + cc;
                                    znext[((size_t)((qr * 2 + qc) * BN + b)) * KDN + pi * 68 + ch] = tv;
                                }
                            }
                        }
                    }
                }
            }
        }
    }
}

// ---------------- old 128x128 kernel (verified) — final tiny GEMM ---------------
template<int EPI, int WS, int WN>
__global__ __launch_bounds__(256)
void gemm_bt(const bf16* __restrict__ A, const bf16* __restrict__ Bm, int KD,
             const float* __restrict__ bias, int ntiles,
             bf16* __restrict__ C, int ldc, int nlimit,
             int m0g, bf16* __restrict__ znext,
             const bf16* __restrict__ afin_xc, float* __restrict__ outp)
{
    __shared__ bf16 As[128 * 32];
    __shared__ bf16 Bs[128 * 32];
    const int tid = threadIdx.x;
    const int wave = tid >> 6, lane = tid & 63;
    const int l15 = lane & 15, lq = lane >> 4;
    const int wr = (wave >> 1) * 64, wc = (wave & 1) * 64;

    const int id = blockIdx.x;
    const int mt8 = (int)gridDim.x / (ntiles * 8);   // m-tiles per XCD
    const int xcd = id & 7, local = id >> 3;
    const int m_idx = xcd * mt8 + local / ntiles;
    const int n_idx = local % ntiles;
    const int n0 = n_idx * 128, m0 = m_idx * 128;

    int nspans = 1, sbeg[4], send[4];
    sbeg[0] = 0; send[0] = KD;
    if (WS > 0) {
        int po_lo = imin(n0 / 68, WS * WS - 1);
        int po_hi = imin((n0 + 127) / 68, WS * WS - 1);
        int ro_lo = po_lo / WS, ro_hi = po_hi / WS;
        int r_lo = imax(ro_lo - 1, 0), r_hi = imin(ro_hi + 1, WS - 1);
        int ci_lo = 0, ci_hi = WS - 1;
        if (ro_lo == ro_hi) {
            ci_lo = imax(po_lo % WS - 1, 0);
            ci_hi = imin(po_hi % WS + 1, WS - 1);
        }
        if (ci_lo == 0 && ci_hi == WS - 1) {
            sbeg[0] = (r_lo * WS * 68) & ~31;
            send[0] = imin(KD, ((r_hi + 1) * WS * 68 + 31) & ~31);
        } else {
            nspans = 0;
            for (int ri = r_lo; ri <= r_hi; ri++) {
                sbeg[nspans] = ((ri * WS + ci_lo) * 68) & ~31;
                send[nspans] = imin(KD, (((ri * WS + ci_hi + 1) * 68) + 31) & ~31);
                nspans++;
            }
        }
    }

    float bj[4];
    #pragma unroll
    for (int j = 0; j < 4; j++) bj[j] = bias[n0 + wc + j * 16 + l15];

    const bf16* Ab = A + (size_t)m0 * KD;
    const bf16* Bb = Bm + (size_t)n0 * KD;
    const int srow = tid >> 2, scol = (tid & 3) * 8;
    const bf16* aG0 = Ab + (size_t)srow * KD + scol;
    const bf16* aG1 = Ab + (size_t)(srow + 64) * KD + scol;
    const bf16* bG0 = Bb + (size_t)srow * KD + scol;
    const bf16* bG1 = Bb + (size_t)(srow + 64) * KD + scol;
    const bf16* lA0 = &As[wave * 512];
    const bf16* lA1 = &As[2048 + wave * 512];
    const bf16* lB0 = &Bs[wave * 512];
    const bf16* lB1 = &Bs[2048 + wave * 512];

    f32x4 acc[4][4];
    #pragma unroll
    for (int i = 0; i < 4; i++)
        #pragma unroll
        for (int j = 0; j < 4; j++) { f32x4 z = {0.f, 0.f, 0.f, 0.f}; acc[i][j] = z; }

    for (int s = 0; s < nspans; s++) {
        for (int k0 = sbeg[s]; k0 < send[s]; k0 += 32) {
            gload_lds16(aG0 + k0, lA0);
            gload_lds16(aG1 + k0, lA1);
            gload_lds16(bG0 + k0, lB0);
            gload_lds16(bG1 + k0, lB1);
            __syncthreads();
            short8 af[4], bg[4];
            #pragma unroll
            for (int i = 0; i < 4; i++) af[i] = *(const short8*)&As[(wr + i * 16 + l15) * 32 + lq * 8];
            #pragma unroll
            for (int j = 0; j < 4; j++) bg[j] = *(const short8*)&Bs[(wc + j * 16 + l15) * 32 + lq * 8];
            #pragma unroll
            for (int i = 0; i < 4; i++)
                #pragma unroll
                for (int j = 0; j < 4; j++)
                    acc[i][j] = __builtin_amdgcn_mfma_f32_16x16x32_bf16(af[i], bg[j], acc[i][j], 0, 0, 0);
            __syncthreads();
        }
    }

    #pragma unroll
    for (int i = 0; i < 4; i++) {
        #pragma unroll
        for (int j = 0; j < 4; j++) {
            int n = n0 + wc + j * 16 + l15;
            #pragma unroll
            for (int r = 0; r < 4; r++) {
                int m = m0 + wr + i * 16 + lq * 4 + r;
                float v = acc[i][j][r];
                if (EPI == 0) {
                    if (n < nlimit) {
                        v += bj[j]; v = fmaxf(v, 0.f); v = sincos_sum(v);
                        C[(size_t)m * ldc + n] = f2b(v);
                    }
                } else if (EPI == 1) {
                    if (n < nlimit) {
                        v += bj[j]; v = fmaxf(v, 0.f);
                        C[(size_t)m * ldc + n] = f2b(v);
                    }
                } else if (EPI == 2) {
                    if (n < 576) {
                        v += bj[j]; v = fmaxf(v, 0.f);
                        bf16 t = f2b(sincos_sum(v));
                        int gm = m0g + m;
                        int q = gm >> 13, b = gm & (BN - 1);
                        int ch = n / 9, p = n % 9;
                        int R = p / 3 + (q >> 1) * 3, Cc = p % 3 + (q & 1) * 3;
                        constexpr int OFF = 6 - WN;
                        constexpr int KDN = (WN == 4) ? 1088 : 640;
                        #pragma unroll
                        for (int qr = 0; qr < 2; qr++) {
                            int rr = R - OFF * qr;
                            if (rr < 0 || rr >= WN) continue;
                            #pragma unroll
                            for (int qc = 0; qc < 2; qc++) {
                                int cc = Cc - OFF * qc;
                                if (cc < 0 || cc >= WN) continue;
                                int pi = rr * WN + cc;
                                znext[((size_t)((qr * 2 + qc) * BN + b)) * KDN + pi * 68 + ch] = t;
                            }
                        }
                    }
                } else {
                    if (n < 64) {
                        v += bj[j];
                        int gm = m0g + m;
                        int f = gm * 64 + n;        // c-flat == out-flat
                        int b2 = f >> 8, rem = f & 255;
                        int ch2 = rem >> 2, ii = (rem >> 1) & 1, jj = rem & 1;
                        int qq = ii * 2 + jj;
                        const int offt[4] = {8, 6, 2, 0};
                        float xc = b2f(afin_xc[((size_t)qq * BN + b2) * 576 + ch2 * 9 + offt[qq]]);
                        outp[f] = v * xc;
                    }
                }
            }
        }
    }
}

extern "C" void kernel_launch(void* const* d_in, const int* in_sizes, int n_in,
                              void* d_out, int out_size, void* d_ws, size_t ws_size,
                              hipStream_t stream)
{
    const float* x    = (const float*)d_in[0];
    const float* cell = (const float*)d_in[1];
    const float* isc  = (const float*)d_in[2];
    const float* c1w  = (const float*)d_in[3];
    const float* c1b  = (const float*)d_in[4];
    const float* c3w  = (const float*)d_in[5];
    const float* c3b  = (const float*)d_in[6];
    const float* l5w  = (const float*)d_in[7];
    const float* l5b  = (const float*)d_in[8];
    const float* l4w  = (const float*)d_in[9];
    const float* l4b  = (const float*)d_in[10];
    const float* l3w  = (const float*)d_in[11];
    const float* l3b  = (const float*)d_in[12];
    const float* fw   = (const float*)d_in[13];
    const float* fb   = (const float*)d_in[14];

    char* base = (char*)d_ws;
    size_t cur = 0;
    auto take = [&](size_t bytes) -> char* {
        char* r = base + cur; cur += (bytes + 255) & ~(size_t)255; return r;
    };

    const size_t Z4B = (size_t)MTOT * 1088 * 2;   // 71.3 MB
    const size_t Z3B = (size_t)MTOT * 640 * 2;    // 41.9 MB
    const size_t AFB = (size_t)MTOT * 576 * 2;    // 37.7 MB
    size_t wbytes = 2 * (1792ull * 1728 + 1152ull * 1088 + 640ull * 640) * 2
                  + (640ull * 1728 + 640ull * 1088 + 640ull * 640) * 2
                  + 128ull * 576 * 2 + 9216ull * 4 + 64 * 256;
    auto need = [&](int nc) -> size_t {
        return Z4B + Z3B + AFB + wbytes + 2 * ((size_t)(MTOT / nc) * 1728 * 2);
    };
    // gemm8 needs CM % 2048 == 0 (mtiles%8 both WIDE variants) -> nchunk<=16 OK
    int nchunk = (ws_size >= need(1)) ? 1 : (ws_size >= need(2)) ? 2
               : (ws_size >= need(4)) ? 4 : (ws_size >= need(8)) ? 8 : 16;

    bf16* Z4   = (bf16*)take(Z4B);
    bf16* Z3   = (bf16*)take(Z3B);
    bf16* afinb = (bf16*)take(AFB);
    bf16* w1d5 = (bf16*)take(1792ull * 1728 * 2);
    bf16* w3d5 = (bf16*)take(1792ull * 1728 * 2);
    bf16* w1d4 = (bf16*)take(1152ull * 1088 * 2);
    bf16* w3d4 = (bf16*)take(1152ull * 1088 * 2);
    bf16* w1d3 = (bf16*)take(640ull * 640 * 2);
    bf16* w3d3 = (bf16*)take(640ull * 640 * 2);
    bf16* wl5p = (bf16*)take(640ull * 1728 * 2);
    bf16* wl4p = (bf16*)take(640ull * 1088 * 2);
    bf16* wl3p = (bf16*)take(640ull * 640 * 2);
    bf16* wfp  = (bf16*)take(128ull * 576 * 2);
    float* biasb = (float*)take(9216ull * 4);
    int CM = MTOT / nchunk;
    int mt = CM / 128;                          // WIDE=1 mtiles + final kernel
    int mt2 = CM / 256;                         // WIDE=0 mtiles
    bf16* Za = (bf16*)take((size_t)CM * 1728 * 2);
    bf16* Zb = (bf16*)take((size_t)CM * 1728 * 2);

    // -------- stage 0: all weight repacks, bias, Z4/Z3 const cols, Z3 pad --------
    {
        constexpr unsigned OT = 2u*1792*1728 + 2u*1152*1088 + 2u*640*640
                              + 640u*1728 + 640u*1088 + 640u*640 + 128u*576 + 9216
                              + 4u*8192*16*4 + 4u*8192*9*4 + 32768u*28;
        megabuild<<<(OT + 255) / 256, 256, 0, stream>>>(
            c1w, c3w, l5w, l4w, l3w, fw, c1b, c3b, l5b, l4b, l3b, fb, cell, isc,
            w1d5, w3d5, w1d4, w3d4, w1d3, w3d3, wl5p, wl4p, wl3p, wfp, biasb, Z4, Z3);
    }

    // -------- ws=5: zprep -> conv1 -> conv3 -> lin (scatter into Z4) -------------
    for (int c = 0; c < nchunk; c++) {
        int m0g = c * CM;
        zprep_block<<<BN, 256, 0, stream>>>(x, cell, isc, Za, m0g, CM);
        gemm8<0, 5, 0, 1><<<512, 512, 0, stream>>>(Za, w1d5, 1728, biasb + 0, 7, mt,
                                                   Zb, 1728, 1728, 0, nullptr);
        gemm8<1, 5, 0, 1><<<512, 512, 0, stream>>>(Zb, w3d5, 1728, biasb + 1792, 7, mt,
                                                   Za, 1728, 1728, 0, nullptr);
        gemm8<2, 0, 4, 0><<<512, 512, 0, stream>>>(Za, wl5p, 1728, biasb + 7168, 5, mt2,
                                                   nullptr, 0, 0, m0g, Z4);
    }
    // -------- ws=4: conv1(Z4) -> conv3 -> lin (scatter into Z3) ------------------
    for (int c = 0; c < nchunk; c++) {
        int m0g = c * CM;
        gemm8<0, 4, 0, 0><<<512, 512, 0, stream>>>(Z4 + (size_t)m0g * 1088, w1d4, 1088,
                                                   biasb + 3584, 9, mt2, Zb, 1088, 1088,
                                                   0, nullptr);
        gemm8<1, 4, 0, 0><<<512, 512, 0, stream>>>(Zb, w3d4, 1088, biasb + 4736, 9, mt2,
                                                   Za, 1088, 1088, 0, nullptr);
        gemm8<2, 0, 3, 0><<<512, 512, 0, stream>>>(Za, wl4p, 1088, biasb + 7808, 5, mt2,
                                                   nullptr, 0, 0, m0g, Z3);
    }
    // -------- ws=3: conv1(Z3) -> conv3 -> lin (-> afinb, identity layout) --------
    for (int c = 0; c < nchunk; c++) {
        int m0g = c * CM;
        gemm8<0, 3, 0, 0><<<512, 512, 0, stream>>>(Z3 + (size_t)m0g * 640, w1d3, 640,
                                                   biasb + 5888, 5, mt2, Zb, 640, 640,
                                                   0, nullptr);
        gemm8<1, 3, 0, 0><<<512, 512, 0, stream>>>(Zb, w3d3, 640, biasb + 6528, 5, mt2,
                                                   Za, 640, 640, 0, nullptr);
        gemm8<1, 0, 0, 0><<<512, 512, 0, stream>>>(Za, wl3p, 640, biasb + 8448, 5, mt2,
                                                   afinb + (size_t)m0g * 576, 576, 576,
                                                   0, nullptr);
    }
    // -------- final: (afinb @ Wf) * xc --------------------------------------------
    for (int c = 0; c < nchunk; c++) {
        int m0g = c * CM;
        gemm_bt<3, 0, 0><<<mt, 256, 0, stream>>>(afinb + (size_t)m0g * 576, wfp, 576,
                                                 biasb + 9088, 1, nullptr, 0, 0, m0g,
                                                 nullptr, afinb, (float*)d_out);
    }
}

// Round 8
// 1178.678 us; speedup vs baseline: 1.5272x; 1.1228x over previous
//
#include <hip/hip_runtime.h>
#include <hip/hip_bf16.h>
#include <cstdint>
#include <cstddef>

#define BN 8192
#define MTOT 32768   // 4*BN

using bf16 = __hip_bfloat16;
typedef float f32x4 __attribute__((ext_vector_type(4)));
typedef short short8 __attribute__((ext_vector_type(8)));

__device__ __forceinline__ bf16 f2b(float v) { return __float2bfloat16(v); }
__device__ __forceinline__ float b2f(bf16 v) { return __bfloat162float(v); }
// sin(x)+cos(x) = sqrt(2)*sin(x+pi/4)
__device__ __forceinline__ float sincos_sum(float x) {
    return 1.41421356237f * __sinf(x + 0.78539816340f);
}

// Layouts are POSITION-MAJOR: k = pi*68 + ic, n = po*68 + oc.

// ---------------- Z0 prep (ws=5 only now), LDS-staged, one block per b ----------
__global__ __launch_bounds__(256)
void zprep_block(const float* __restrict__ xF, const float* __restrict__ cell,
                 const float* __restrict__ isc, bf16* __restrict__ Z,
                 int m0g, int CM)
{
    constexpr int KD = 1728, KTRUE = 1700;
    const int b = blockIdx.x, tid = threadIdx.x;
    __shared__ float s[68][37];   // stride 37 words (mod 32 = 5) -> conflict-free

    for (int i = tid; i < 64 * 36; i += 256) {
        int ic = i / 36, off = i % 36;
        s[ic][off] = sincos_sum(xF[((size_t)b * 64 + ic) * 36 + off]);
    }
    if (tid < 2) {
        float t = sincos_sum(cell[b * 2 + tid]);
        #pragma unroll
        for (int off = 0; off < 36; off++) s[64 + tid][off] = t;
    }
    if (tid >= 64 && tid < 136) {
        int j = tid - 64;
        int ic = j / 36, off = j % 36;
        s[66 + ic][off] = sincos_sum(isc[((size_t)b * 2 + ic) * 36 + off]);
    }
    __syncthreads();

    // vectorized: 8 consecutive k per thread -> short8 store (16B, coalesced)
    for (int i = tid; i < 4 * (KD / 8); i += 256) {
        int q = i / (KD / 8), j8 = i % (KD / 8);
        int gm = q * BN + b;
        if (gm < m0g || gm >= m0g + CM) continue;
        int kbase = j8 * 8;
        short8 pack;
        #pragma unroll
        for (int u = 0; u < 8; u++) {
            int k = kbase + u;
            float v = 0.f;
            if (k < KTRUE) {
                int pi = k / 68, ic = k % 68;
                int r = (q >> 1) + pi / 5;       // (6-WS)=1
                int c = (q & 1) + pi % 5;
                v = s[ic][r * 6 + c];
            }
            bf16 bv = f2b(v);
            pack[u] = *reinterpret_cast<short*>(&bv);
        }
        *reinterpret_cast<short8*>(&Z[(size_t)(gm - m0g) * KD + kbase]) = pack;
    }
}

// ---------------- megabuild: all weights/bias/const-cols in ONE kernel -----------
template<int WSv>
__device__ __forceinline__ bf16 conv_elem(const float* __restrict__ src, int n, int k)
{
    constexpr int KTRUE = 68 * WSv * WSv;
    float v = 0.f;
    if (n < KTRUE && k < KTRUE) {
        int po = n / 68, oc = n % 68, ro = po / WSv, co = po % WSv;
        int pi = k / 68, ic = k % 68, ri = pi / WSv, ci = pi % WSv;
        int kr = ri - ro + 1, kc = ci - co + 1;
        if (kr >= 0 && kr < 3 && kc >= 0 && kc < 3)
            v = src[((oc * 68 + ic) * 3 + kr) * 3 + kc];
    }
    return f2b(v);
}
template<int WSv>
__device__ __forceinline__ bf16 lin_elem(const float* __restrict__ wl, int n, int k)
{
    constexpr int KTRUE = 68 * WSv * WSv;
    float v = 0.f;
    if (n < 576 && k < KTRUE) {
        int pi = k / 68, ic = k % 68;
        v = wl[(size_t)n * KTRUE + ic * (WSv * WSv) + pi];  // ref k-order = ic*ws^2+pi
    }
    return f2b(v);
}

__global__ void megabuild(const float* __restrict__ c1w, const float* __restrict__ c3w,
                          const float* __restrict__ l5w, const float* __restrict__ l4w,
                          const float* __restrict__ l3w, const float* __restrict__ fw,
                          const float* __restrict__ c1b, const float* __restrict__ c3b,
                          const float* __restrict__ bl5, const float* __restrict__ bl4,
                          const float* __restrict__ bl3, const float* __restrict__ bfin,
                          const float* __restrict__ cell, const float* __restrict__ isc,
                          bf16* __restrict__ w1d5, bf16* __restrict__ w3d5,
                          bf16* __restrict__ w1d4, bf16* __restrict__ w3d4,
                          bf16* __restrict__ w1d3, bf16* __restrict__ w3d3,
                          bf16* __restrict__ wl5p, bf16* __restrict__ wl4p,
                          bf16* __restrict__ wl3p, bf16* __restrict__ wfp,
                          float* __restrict__ bias,
                          bf16* __restrict__ Z4, bf16* __restrict__ Z3)
{
    constexpr unsigned S0 = 2u*1792*1728, S1 = 2u*1152*1088, S2 = 2u*640*640;
    constexpr unsigned S3 = 640u*1728, S4 = 640u*1088, S5 = 640u*640;
    constexpr unsigned S6 = 128u*576, S7 = 9216;
    constexpr unsigned S8 = 4u*8192*16*4, S9 = 4u*8192*9*4, S10 = 32768u*28;
    constexpr unsigned O1=S0, O2=O1+S1, O3=O2+S2, O4=O3+S3, O5=O4+S4, O6=O5+S5,
                       O7=O6+S6, O8=O7+S7, O9=O8+S8, O10=O9+S9, OT=O10+S10;
    unsigned e = blockIdx.x * 256u + threadIdx.x;
    if (e >= OT) return;
    if (e < O1) {
        constexpr unsigned per = 1792u*1728;
        unsigned i = (e < per) ? e : e - per;
        bf16* dst = (e < per) ? w1d5 : w3d5;
        const float* src = (e < per) ? c1w : c3w;
        dst[i] = conv_elem<5>(src, (int)(i / 1728u), (int)(i % 1728u));
    } else if (e < O2) {
        unsigned i0 = e - O1; constexpr unsigned per = 1152u*1088;
        unsigned i = (i0 < per) ? i0 : i0 - per;
        bf16* dst = (i0 < per) ? w1d4 : w3d4;
        const float* src = (i0 < per) ? c1w : c3w;
        dst[i] = conv_elem<4>(src, (int)(i / 1088u), (int)(i % 1088u));
    } else if (e < O3) {
        unsigned i0 = e - O2; constexpr unsigned per = 640u*640;
        unsigned i = (i0 < per) ? i0 : i0 - per;
        bf16* dst = (i0 < per) ? w1d3 : w3d3;
        const float* src = (i0 < per) ? c1w : c3w;
        dst[i] = conv_elem<3>(src, (int)(i / 640u), (int)(i % 640u));
    } else if (e < O4) {
        unsigned i = e - O3;
        wl5p[i] = lin_elem<5>(l5w, (int)(i / 1728u), (int)(i % 1728u));
    } else if (e < O5) {
        unsigned i = e - O4;
        wl4p[i] = lin_elem<4>(l4w, (int)(i / 1088u), (int)(i % 1088u));
    } else if (e < O6) {
        unsigned i = e - O5;
        wl3p[i] = lin_elem<3>(l3w, (int)(i / 640u), (int)(i % 640u));
    } else if (e < O7) {
        unsigned i = e - O6, n = i / 576u, k = i % 576u;
        wfp[i] = (n < 64u) ? f2b(fw[n * 576u + k]) : f2b(0.f);
    } else if (e < O8) {
        int i = (int)(e - O7);
        float v = 0.f;
        if (i < 1792)      { int n = i;        if (n < 1700) v = c1b[n % 68]; }
        else if (i < 3584) { int n = i - 1792; if (n < 1700) v = c3b[n % 68]; }
        else if (i < 4736) { int n = i - 3584; if (n < 1088) v = c1b[n % 68]; }
        else if (i < 5888) { int n = i - 4736; if (n < 1088) v = c3b[n % 68]; }
        else if (i < 6528) { int n = i - 5888; if (n < 612)  v = c1b[n % 68]; }
        else if (i < 7168) { int n = i - 6528; if (n < 612)  v = c3b[n % 68]; }
        else if (i < 7808) { int n = i - 7168; if (n < 576)  v = bl5[n]; }
        else if (i < 8448) { int n = i - 7808; if (n < 576)  v = bl4[n]; }
        else if (i < 9088) { int n = i - 8448; if (n < 576)  v = bl3[n]; }
        else               { int n = i - 9088; if (n < 64)   v = bfin[n]; }
        bias[i] = v;
    } else if (e < O9) {
        // Z4 const cols (cell/isc), ic = 64..67
        unsigned i = e - O8;
        int j = (int)(i & 3u); i >>= 2;
        int pi = (int)(i & 15u); i >>= 4;
        int b = (int)(i & 8191u); int q = (int)(i >> 13);
        float t;
        if (j < 2) t = cell[b * 2 + j];
        else {
            int r = (q >> 1) * 2 + pi / 4, c = (q & 1) * 2 + pi % 4;
            t = isc[((size_t)b * 2 + (j - 2)) * 36 + r * 6 + c];
        }
        Z4[((size_t)q * BN + b) * 1088 + pi * 68 + 64 + j] = f2b(sincos_sum(t));
    } else if (e < O10) {
        // Z3 const cols
        unsigned i = e - O9;
        int j = (int)(i & 3u); i >>= 2;
        int pi = (int)(i % 9u); i /= 9u;
        int b = (int)(i & 8191u); int q = (int)(i >> 13);
        float t;
        if (j < 2) t = cell[b * 2 + j];
        else {
            int r = (q >> 1) * 3 + pi / 3, c = (q & 1) * 3 + pi % 3;
            t = isc[((size_t)b * 2 + (j - 2)) * 36 + r * 6 + c];
        }
        Z3[((size_t)q * BN + b) * 640 + pi * 68 + 64 + j] = f2b(sincos_sum(t));
    } else {
        // Z3 pad cols 612..639 = 0 (avoid NaN-poison from workspace)
        unsigned i = e - O10;
        int m = (int)(i / 28u), t = (int)(i % 28u);
        Z3[(size_t)m * 640 + 612 + t] = f2b(0.f);
    }
}

// ---------------- async global->LDS, 16B per lane (m97 idiom) --------------------
__device__ __forceinline__ void gload_lds16(const bf16* g, const bf16* lds_wave_base)
{
    unsigned off = (unsigned)(uintptr_t)lds_wave_base;
    off = __builtin_amdgcn_readfirstlane(off);
    __builtin_amdgcn_global_load_lds((const __attribute__((address_space(1))) unsigned int*)g,
                                     (__attribute__((address_space(3))) unsigned int*)off,
                                     16, 0, 0);
}

__device__ __forceinline__ int imin(int a, int b) { return a < b ? a : b; }
__device__ __forceinline__ int imax(int a, int b) { return a > b ? a : b; }

// =============================================================================
// gemm8 (r5 pipeline core + PANEL-MAJOR tile order for XCD-L2 reuse):
//   WIDE=0: BM=256, BN=128 ; WIDE=1: BM=128, BN=256 (conv5 pair).
// 8 waves, BK=32, triple-buffered LDS (72 KiB -> 2 blocks/CU), ONE barrier per
// K-tile, counted vmcnt(3) (never 0 mid-loop), conflict-free XOR swizzle at
// BOTH pre-swizzled global source and ds_read (SQ_LDS_BANK_CONFLICT=0, r3),
// setprio around MFMA. All verified r3-r5; epilogue = scalar (r5, verified;
// r7's LDS-transpose epilogue regressed total and is reverted).
// NEW (r8): diagnosis across r3-r7 shows every config saturates ~11-14 TB/s of
// L2/L3 fabric read traffic while no CU-side counter is saturated -> the chain
// is fabric-BW bound. Tile enumeration is now PANEL-MAJOR: within each XCD,
// tiles are ordered (panel of P=4 m-tiles) x (n) x (m-in-panel, innermost), so
// co-resident blocks share one A-panel-band (~1 MB) + active B-bands in the
// 4 MB XCD L2. A is then fetched from L3 ~once per panel instead of once per
// n-tile; B (L2-sized for all non-conv5 GEMMs) stays resident. Pure scheduling
// change - results bit-identical.
// EPI: 0 bias+relu+sincos->C ; 1 bias+relu->C ;
//      2 bias+relu+sincos -> scatter into Z_next (window WN)
// =============================================================================
template<int EPI, int WS, int WN, int WIDE>
__global__ __launch_bounds__(512, 4)
void gemm8(const bf16* __restrict__ A, const bf16* __restrict__ Bm, int KD,
           const float* __restrict__ bias, int ntiles, int mtiles,
           bf16* __restrict__ C, int ldc, int nlimit,
           int m0g, bf16* __restrict__ znext)
{
    constexpr int BMc = WIDE ? 128 : 256;
    constexpr int BNc = WIDE ? 256 : 128;
    constexpr int NWN = WIDE ? 4 : 2;            // waves along N
    __shared__ bf16 As[3][BMc * 32];
    __shared__ bf16 Bs[3][BNc * 32];
    const int tid = threadIdx.x;
    const int wave = tid >> 6, lane = tid & 63;
    const int l15 = lane & 15, lq = lane >> 4;
    const int wr = (wave / NWN) * 64, wc = (wave % NWN) * 64;

    // ---- panel-major tile mapping (grid = ntiles * mtiles, mtiles % 8 == 0) ----
    const int xcd = blockIdx.x & 7, local = blockIdx.x >> 3;
    const int mloc = mtiles >> 3;                // m-tiles per XCD
    const int PP = (mloc >= 4) ? 4 : mloc;       // panel size (divides mloc)
    const int grp = ntiles * PP;
    const int p = local / grp, rem = local % grp;
    const int n_idx = rem / PP, mi = rem % PP;
    const int m_idx = xcd * mloc + p * PP + mi;
    const int n0 = n_idx * BNc, m0 = m_idx * BMc;

    // ---- K-banding spans (32-aligned) ----
    int s0b = 0, s0e = KD, s1b = 0, s1e = 0, s2b = 0, s2e = 0;
    if (WS > 0) {
        int po_lo = imin(n0 / 68, WS * WS - 1);
        int po_hi = imin((n0 + BNc - 1) / 68, WS * WS - 1);
        int ro_lo = po_lo / WS, ro_hi = po_hi / WS;
        int r_lo = imax(ro_lo - 1, 0), r_hi = imin(ro_hi + 1, WS - 1);
        int ci_lo = 0, ci_hi = WS - 1;
        if (ro_lo == ro_hi) {
            ci_lo = imax(po_lo % WS - 1, 0);
            ci_hi = imin(po_hi % WS + 1, WS - 1);
        }
        if (ci_lo == 0 && ci_hi == WS - 1) {
            s0b = (r_lo * WS * 68) & ~31;
            s0e = imin(KD, ((r_hi + 1) * WS * 68 + 31) & ~31);
        } else {
            s0b = ((r_lo * WS + ci_lo) * 68) & ~31;
            s0e = imin(KD, (((r_lo * WS + ci_hi + 1) * 68) + 31) & ~31);
            if (r_hi > r_lo) {
                s1b = (((r_lo + 1) * WS + ci_lo) * 68) & ~31;
                s1e = imin(KD, ((((r_lo + 1) * WS + ci_hi + 1) * 68) + 31) & ~31);
            }
            if (r_hi > r_lo + 1) {
                s2b = (((r_lo + 2) * WS + ci_lo) * 68) & ~31;
                s2e = imin(KD, ((((r_lo + 2) * WS + ci_hi + 1) * 68) + 31) & ~31);
            }
        }
    }
    const int c0 = (s0e - s0b) >> 5;
    const int c1 = c0 + ((s1e - s1b) >> 5);
    const int nt = c1 + ((s2e - s2b) >> 5);
    auto k0_of = [&](int t2) -> int {
        int k = s0b + (t2 << 5);
        if (t2 >= c0) k = s1b + ((t2 - c0) << 5);
        if (t2 >= c1) k = s2b + ((t2 - c1) << 5);
        return k;
    };

    // ---- staging addressing: linear LDS dest, pre-swizzled global source ----
    const int srow = tid >> 2;
    const int scx = (tid & 3) ^ ((srow >> 1) & 3);
    const int sOff = srow * 32 + (tid & 3) * 8;
    // fragment read swizzle: row = 16-aligned + l15 -> (row>>1)&3 = (l15>>1)&3
    const int swz = (lq ^ ((l15 >> 1) & 3)) * 8;
    const int offA0 = (wr + l15) * 32 + swz;     // + i*512
    const int offB0 = (wc + l15) * 32 + swz;     // + j*512

    const bf16* aSrc = A + (size_t)(m0 + srow) * KD + scx * 8;
    const bf16* bSrc = Bm + (size_t)(n0 + srow) * KD + scx * 8;

    auto stageAll = [&](int k0, int buf) {   // 3 loads total
        if (WIDE) {
            gload_lds16(aSrc + k0, &As[buf][sOff]);
            gload_lds16(bSrc + k0, &Bs[buf][sOff]);
            gload_lds16(bSrc + k0 + (size_t)128 * KD, &Bs[buf][sOff + 4096]);
        } else {
            gload_lds16(aSrc + k0, &As[buf][sOff]);
            gload_lds16(aSrc + k0 + (size_t)128 * KD, &As[buf][sOff + 4096]);
            gload_lds16(bSrc + k0, &Bs[buf][sOff]);
        }
    };

    f32x4 acc[4][4];
    #pragma unroll
    for (int i = 0; i < 4; i++)
        #pragma unroll
        for (int j = 0; j < 4; j++) { f32x4 z = {0.f, 0.f, 0.f, 0.f}; acc[i][j] = z; }

    // ---- prologue: stage tiles 0,1; full drain ----
    {
        stageAll(k0_of(0), 0);
        if (nt > 1) stageAll(k0_of(1), 1);
        __syncthreads();
    }

    // ---- main loop: one barrier per K-tile (r3-r5 verified ledger) ----
    for (int t = 0; t < nt; ++t) {
        const int cur = t % 3;
        const int nx = (t + 2) % 3;
        const bool pf = (t + 2) < nt;

        const bf16* Ac = &As[cur][0];
        const bf16* Bc = &Bs[cur][0];

        short8 af[4], bg[4];
        #pragma unroll
        for (int i = 0; i < 4; i++) af[i] = *(const short8*)&Ac[offA0 + i * 512];
        #pragma unroll
        for (int j = 0; j < 4; j++) bg[j] = *(const short8*)&Bc[offB0 + j * 512];

        if (pf) stageAll(k0_of(t + 2), nx);

        __builtin_amdgcn_s_setprio(1);
        #pragma unroll
        for (int i = 0; i < 4; i++)
            #pragma unroll
            for (int j = 0; j < 4; j++)
                acc[i][j] = __builtin_amdgcn_mfma_f32_16x16x32_bf16(af[i], bg[j], acc[i][j], 0, 0, 0);
        __builtin_amdgcn_s_setprio(0);

        if (pf) asm volatile("s_waitcnt vmcnt(3)" ::: "memory");
        else    asm volatile("s_waitcnt vmcnt(0)" ::: "memory");
        __builtin_amdgcn_s_barrier();
    }

    // ---- epilogue (scalar, r5-verified) ----
    float bj[4];
    #pragma unroll
    for (int j = 0; j < 4; j++) bj[j] = bias[n0 + wc + j * 16 + l15];

    #pragma unroll
    for (int i = 0; i < 4; i++) {
        #pragma unroll
        for (int j = 0; j < 4; j++) {
            int n = n0 + wc + j * 16 + l15;
            #pragma unroll
            for (int r = 0; r < 4; r++) {
                int m = m0 + wr + i * 16 + lq * 4 + r;
                float v = acc[i][j][r];
                if (EPI == 0) {
                    if (n < nlimit) {
                        v += bj[j]; v = fmaxf(v, 0.f); v = sincos_sum(v);
                        C[(size_t)m * ldc + n] = f2b(v);
                    }
                } else if (EPI == 1) {
                    if (n < nlimit) {
                        v += bj[j]; v = fmaxf(v, 0.f);
                        C[(size_t)m * ldc + n] = f2b(v);
                    }
                } else {
                    if (n < 576) {
                        v += bj[j]; v = fmaxf(v, 0.f);
                        bf16 tv = f2b(sincos_sum(v));
                        int gm = m0g + m;
                        int q = gm >> 13, b = gm & (BN - 1);
                        int ch = n / 9, p2 = n % 9;
                        int R = p2 / 3 + (q >> 1) * 3, Cc = p2 % 3 + (q & 1) * 3;
                        constexpr int OFF = 6 - WN;
                        constexpr int KDN = (WN == 4) ? 1088 : 640;
                        #pragma unroll
                        for (int qr = 0; qr < 2; qr++) {
                            int rr = R - OFF * qr;
                            if (rr < 0 || rr >= WN) continue;
                            #pragma unroll
                            for (int qc = 0; qc < 2; qc++) {
                                int cc = Cc - OFF * qc;
                                if (cc < 0 || cc >= WN) continue;
                                int pi = rr * WN + cc;
                                znext[((size_t)((qr * 2 + qc) * BN + b)) * KDN + pi * 68 + ch] = tv;
                            }
                        }
                    }
                }
            }
        }
    }
}

// ---------------- old 128x128 kernel (verified) — final tiny GEMM ---------------
template<int EPI, int WS, int WN>
__global__ __launch_bounds__(256)
void gemm_bt(const bf16* __restrict__ A, const bf16* __restrict__ Bm, int KD,
             const float* __restrict__ bias, int ntiles,
             bf16* __restrict__ C, int ldc, int nlimit,
             int m0g, bf16* __restrict__ znext,
             const bf16* __restrict__ afin_xc, float* __restrict__ outp)
{
    __shared__ bf16 As[128 * 32];
    __shared__ bf16 Bs[128 * 32];
    const int tid = threadIdx.x;
    const int wave = tid >> 6, lane = tid & 63;
    const int l15 = lane & 15, lq = lane >> 4;
    const int wr = (wave >> 1) * 64, wc = (wave & 1) * 64;

    const int id = blockIdx.x;
    const int mt8 = (int)gridDim.x / (ntiles * 8);   // m-tiles per XCD
    const int xcd = id & 7, local = id >> 3;
    const int m_idx = xcd * mt8 + local / ntiles;
    const int n_idx = local % ntiles;
    const int n0 = n_idx * 128, m0 = m_idx * 128;

    int nspans = 1, sbeg[4], send[4];
    sbeg[0] = 0; send[0] = KD;
    if (WS > 0) {
        int po_lo = imin(n0 / 68, WS * WS - 1);
        int po_hi = imin((n0 + 127) / 68, WS * WS - 1);
        int ro_lo = po_lo / WS, ro_hi = po_hi / WS;
        int r_lo = imax(ro_lo - 1, 0), r_hi = imin(ro_hi + 1, WS - 1);
        int ci_lo = 0, ci_hi = WS - 1;
        if (ro_lo == ro_hi) {
            ci_lo = imax(po_lo % WS - 1, 0);
            ci_hi = imin(po_hi % WS + 1, WS - 1);
        }
        if (ci_lo == 0 && ci_hi == WS - 1) {
            sbeg[0] = (r_lo * WS * 68) & ~31;
            send[0] = imin(KD, ((r_hi + 1) * WS * 68 + 31) & ~31);
        } else {
            nspans = 0;
            for (int ri = r_lo; ri <= r_hi; ri++) {
                sbeg[nspans] = ((ri * WS + ci_lo) * 68) & ~31;
                send[nspans] = imin(KD, (((ri * WS + ci_hi + 1) * 68) + 31) & ~31);
                nspans++;
            }
        }
    }

    float bj[4];
    #pragma unroll
    for (int j = 0; j < 4; j++) bj[j] = bias[n0 + wc + j * 16 + l15];

    const bf16* Ab = A + (size_t)m0 * KD;
    const bf16* Bb = Bm + (size_t)n0 * KD;
    const int srow = tid >> 2, scol = (tid & 3) * 8;
    const bf16* aG0 = Ab + (size_t)srow * KD + scol;
    const bf16* aG1 = Ab + (size_t)(srow + 64) * KD + scol;
    const bf16* bG0 = Bb + (size_t)srow * KD + scol;
    const bf16* bG1 = Bb + (size_t)(srow + 64) * KD + scol;
    const bf16* lA0 = &As[wave * 512];
    const bf16* lA1 = &As[2048 + wave * 512];
    const bf16* lB0 = &Bs[wave * 512];
    const bf16* lB1 = &Bs[2048 + wave * 512];

    f32x4 acc[4][4];
    #pragma unroll
    for (int i = 0; i < 4; i++)
        #pragma unroll
        for (int j = 0; j < 4; j++) { f32x4 z = {0.f, 0.f, 0.f, 0.f}; acc[i][j] = z; }

    for (int s = 0; s < nspans; s++) {
        for (int k0 = sbeg[s]; k0 < send[s]; k0 += 32) {
            gload_lds16(aG0 + k0, lA0);
            gload_lds16(aG1 + k0, lA1);
            gload_lds16(bG0 + k0, lB0);
            gload_lds16(bG1 + k0, lB1);
            __syncthreads();
            short8 af[4], bg[4];
            #pragma unroll
            for (int i = 0; i < 4; i++) af[i] = *(const short8*)&As[(wr + i * 16 + l15) * 32 + lq * 8];
            #pragma unroll
            for (int j = 0; j < 4; j++) bg[j] = *(const short8*)&Bs[(wc + j * 16 + l15) * 32 + lq * 8];
            #pragma unroll
            for (int i = 0; i < 4; i++)
                #pragma unroll
                for (int j = 0; j < 4; j++)
                    acc[i][j] = __builtin_amdgcn_mfma_f32_16x16x32_bf16(af[i], bg[j], acc[i][j], 0, 0, 0);
            __syncthreads();
        }
    }

    #pragma unroll
    for (int i = 0; i < 4; i++) {
        #pragma unroll
        for (int j = 0; j < 4; j++) {
            int n = n0 + wc + j * 16 + l15;
            #pragma unroll
            for (int r = 0; r < 4; r++) {
                int m = m0 + wr + i * 16 + lq * 4 + r;
                float v = acc[i][j][r];
                if (EPI == 0) {
                    if (n < nlimit) {
                        v += bj[j]; v = fmaxf(v, 0.f); v = sincos_sum(v);
                        C[(size_t)m * ldc + n] = f2b(v);
                    }
                } else if (EPI == 1) {
                    if (n < nlimit) {
                        v += bj[j]; v = fmaxf(v, 0.f);
                        C[(size_t)m * ldc + n] = f2b(v);
                    }
                } else if (EPI == 2) {
                    if (n < 576) {
                        v += bj[j]; v = fmaxf(v, 0.f);
                        bf16 t = f2b(sincos_sum(v));
                        int gm = m0g + m;
                        int q = gm >> 13, b = gm & (BN - 1);
                        int ch = n / 9, p = n % 9;
                        int R = p / 3 + (q >> 1) * 3, Cc = p % 3 + (q & 1) * 3;
                        constexpr int OFF = 6 - WN;
                        constexpr int KDN = (WN == 4) ? 1088 : 640;
                        #pragma unroll
                        for (int qr = 0; qr < 2; qr++) {
                            int rr = R - OFF * qr;
                            if (rr < 0 || rr >= WN) continue;
                            #pragma unroll
                            for (int qc = 0; qc < 2; qc++) {
                                int cc = Cc - OFF * qc;
                                if (cc < 0 || cc >= WN) continue;
                                int pi = rr * WN + cc;
                                znext[((size_t)((qr * 2 + qc) * BN + b)) * KDN + pi * 68 + ch] = t;
                            }
                        }
                    }
                } else {
                    if (n < 64) {
                        v += bj[j];
                        int gm = m0g + m;
                        int f = gm * 64 + n;        // c-flat == out-flat
                        int b2 = f >> 8, rem = f & 255;
                        int ch2 = rem >> 2, ii = (rem >> 1) & 1, jj = rem & 1;
                        int qq = ii * 2 + jj;
                        const int offt[4] = {8, 6, 2, 0};
                        float xc = b2f(afin_xc[((size_t)qq * BN + b2) * 576 + ch2 * 9 + offt[qq]]);
                        outp[f] = v * xc;
                    }
                }
            }
        }
    }
}

extern "C" void kernel_launch(void* const* d_in, const int* in_sizes, int n_in,
                              void* d_out, int out_size, void* d_ws, size_t ws_size,
                              hipStream_t stream)
{
    const float* x    = (const float*)d_in[0];
    const float* cell = (const float*)d_in[1];
    const float* isc  = (const float*)d_in[2];
    const float* c1w  = (const float*)d_in[3];
    const float* c1b  = (const float*)d_in[4];
    const float* c3w  = (const float*)d_in[5];
    const float* c3b  = (const float*)d_in[6];
    const float* l5w  = (const float*)d_in[7];
    const float* l5b  = (const float*)d_in[8];
    const float* l4w  = (const float*)d_in[9];
    const float* l4b  = (const float*)d_in[10];
    const float* l3w  = (const float*)d_in[11];
    const float* l3b  = (const float*)d_in[12];
    const float* fw   = (const float*)d_in[13];
    const float* fb   = (const float*)d_in[14];

    char* base = (char*)d_ws;
    size_t cur = 0;
    auto take = [&](size_t bytes) -> char* {
        char* r = base + cur; cur += (bytes + 255) & ~(size_t)255; return r;
    };

    const size_t Z4B = (size_t)MTOT * 1088 * 2;   // 71.3 MB
    const size_t Z3B = (size_t)MTOT * 640 * 2;    // 41.9 MB
    const size_t AFB = (size_t)MTOT * 576 * 2;    // 37.7 MB
    size_t wbytes = 2 * (1792ull * 1728 + 1152ull * 1088 + 640ull * 640) * 2
                  + (640ull * 1728 + 640ull * 1088 + 640ull * 640) * 2
                  + 128ull * 576 * 2 + 9216ull * 4 + 64 * 256;
    auto need = [&](int nc) -> size_t {
        return Z4B + Z3B + AFB + wbytes + 2 * ((size_t)(MTOT / nc) * 1728 * 2);
    };
    // gemm8 needs CM % 2048 == 0 (mtiles%8 both WIDE variants) -> nchunk<=16 OK
    int nchunk = (ws_size >= need(1)) ? 1 : (ws_size >= need(2)) ? 2
               : (ws_size >= need(4)) ? 4 : (ws_size >= need(8)) ? 8 : 16;

    bf16* Z4   = (bf16*)take(Z4B);
    bf16* Z3   = (bf16*)take(Z3B);
    bf16* afinb = (bf16*)take(AFB);
    bf16* w1d5 = (bf16*)take(1792ull * 1728 * 2);
    bf16* w3d5 = (bf16*)take(1792ull * 1728 * 2);
    bf16* w1d4 = (bf16*)take(1152ull * 1088 * 2);
    bf16* w3d4 = (bf16*)take(1152ull * 1088 * 2);
    bf16* w1d3 = (bf16*)take(640ull * 640 * 2);
    bf16* w3d3 = (bf16*)take(640ull * 640 * 2);
    bf16* wl5p = (bf16*)take(640ull * 1728 * 2);
    bf16* wl4p = (bf16*)take(640ull * 1088 * 2);
    bf16* wl3p = (bf16*)take(640ull * 640 * 2);
    bf16* wfp  = (bf16*)take(128ull * 576 * 2);
    float* biasb = (float*)take(9216ull * 4);
    int CM = MTOT / nchunk;
    int mt = CM / 128;                          // WIDE=1 mtiles + final kernel
    int mt2 = CM / 256;                         // WIDE=0 mtiles
    bf16* Za = (bf16*)take((size_t)CM * 1728 * 2);
    bf16* Zb = (bf16*)take((size_t)CM * 1728 * 2);

    // -------- stage 0: all weight repacks, bias, Z4/Z3 const cols, Z3 pad --------
    {
        constexpr unsigned OT = 2u*1792*1728 + 2u*1152*1088 + 2u*640*640
                              + 640u*1728 + 640u*1088 + 640u*640 + 128u*576 + 9216
                              + 4u*8192*16*4 + 4u*8192*9*4 + 32768u*28;
        megabuild<<<(OT + 255) / 256, 256, 0, stream>>>(
            c1w, c3w, l5w, l4w, l3w, fw, c1b, c3b, l5b, l4b, l3b, fb, cell, isc,
            w1d5, w3d5, w1d4, w3d4, w1d3, w3d3, wl5p, wl4p, wl3p, wfp, biasb, Z4, Z3);
    }

    // -------- ws=5: zprep -> conv1 -> conv3 -> lin (scatter into Z4) -------------
    // conv5 pair: WIDE=1 (BM=128 x BN=256, 7 n-tiles) — halves A compulsory traffic
    for (int c = 0; c < nchunk; c++) {
        int m0g = c * CM;
        zprep_block<<<BN, 256, 0, stream>>>(x, cell, isc, Za, m0g, CM);
        gemm8<0, 5, 0, 1><<<7 * mt, 512, 0, stream>>>(Za, w1d5, 1728, biasb + 0, 7, mt,
                                                      Zb, 1728, 1728, 0, nullptr);
        gemm8<1, 5, 0, 1><<<7 * mt, 512, 0, stream>>>(Zb, w3d5, 1728, biasb + 1792, 7, mt,
                                                      Za, 1728, 1728, 0, nullptr);
        gemm8<2, 0, 4, 0><<<5 * mt2, 512, 0, stream>>>(Za, wl5p, 1728, biasb + 7168, 5, mt2,
                                                       nullptr, 0, 0, m0g, Z4);
    }
    // -------- ws=4: conv1(Z4) -> conv3 -> lin (scatter into Z3) ------------------
    for (int c = 0; c < nchunk; c++) {
        int m0g = c * CM;
        gemm8<0, 4, 0, 0><<<9 * mt2, 512, 0, stream>>>(Z4 + (size_t)m0g * 1088, w1d4, 1088,
                                                       biasb + 3584, 9, mt2, Zb, 1088, 1088,
                                                       0, nullptr);
        gemm8<1, 4, 0, 0><<<9 * mt2, 512, 0, stream>>>(Zb, w3d4, 1088, biasb + 4736, 9, mt2,
                                                       Za, 1088, 1088, 0, nullptr);
        gemm8<2, 0, 3, 0><<<5 * mt2, 512, 0, stream>>>(Za, wl4p, 1088, biasb + 7808, 5, mt2,
                                                       nullptr, 0, 0, m0g, Z3);
    }
    // -------- ws=3: conv1(Z3) -> conv3 -> lin (-> afinb, identity layout) --------
    for (int c = 0; c < nchunk; c++) {
        int m0g = c * CM;
        gemm8<0, 3, 0, 0><<<5 * mt2, 512, 0, stream>>>(Z3 + (size_t)m0g * 640, w1d3, 640,
                                                       biasb + 5888, 5, mt2, Zb, 640, 640,
                                                       0, nullptr);
        gemm8<1, 3, 0, 0><<<5 * mt2, 512, 0, stream>>>(Zb, w3d3, 640, biasb + 6528, 5, mt2,
                                                       Za, 640, 640, 0, nullptr);
        gemm8<1, 0, 0, 0><<<5 * mt2, 512, 0, stream>>>(Za, wl3p, 640, biasb + 8448, 5, mt2,
                                                       afinb + (size_t)m0g * 576, 576, 576,
                                                       0, nullptr);
    }
    // -------- final: (afinb @ Wf) * xc --------------------------------------------
    for (int c = 0; c < nchunk; c++) {
        int m0g = c * CM;
        gemm_bt<3, 0, 0><<<mt, 256, 0, stream>>>(afinb + (size_t)m0g * 576, wfp, 576,
                                                 biasb + 9088, 1, nullptr, 0, 0, m0g,
                                                 nullptr, afinb, (float*)d_out);
    }
}

// Round 9
// 1172.225 us; speedup vs baseline: 1.5356x; 1.0055x over previous
//
#include <hip/hip_runtime.h>
#include <hip/hip_bf16.h>
#include <cstdint>
#include <cstddef>

#define BN 8192
#define MTOT 32768   // 4*BN

using bf16 = __hip_bfloat16;
typedef float f32x4 __attribute__((ext_vector_type(4)));
typedef short short8 __attribute__((ext_vector_type(8)));

__device__ __forceinline__ bf16 f2b(float v) { return __float2bfloat16(v); }
__device__ __forceinline__ float b2f(bf16 v) { return __bfloat162float(v); }
// sin(x)+cos(x) = sqrt(2)*sin(x+pi/4)
__device__ __forceinline__ float sincos_sum(float x) {
    return 1.41421356237f * __sinf(x + 0.78539816340f);
}

// Layouts are POSITION-MAJOR: k = pi*68 + ic, n = po*68 + oc.

// ---------------- Z0 prep (ws=5 only now), LDS-staged, one block per b ----------
__global__ __launch_bounds__(256)
void zprep_block(const float* __restrict__ xF, const float* __restrict__ cell,
                 const float* __restrict__ isc, bf16* __restrict__ Z,
                 int m0g, int CM)
{
    constexpr int KD = 1728, KTRUE = 1700;
    const int b = blockIdx.x, tid = threadIdx.x;
    __shared__ float s[68][37];   // stride 37 words (mod 32 = 5) -> conflict-free

    for (int i = tid; i < 64 * 36; i += 256) {
        int ic = i / 36, off = i % 36;
        s[ic][off] = sincos_sum(xF[((size_t)b * 64 + ic) * 36 + off]);
    }
    if (tid < 2) {
        float t = sincos_sum(cell[b * 2 + tid]);
        #pragma unroll
        for (int off = 0; off < 36; off++) s[64 + tid][off] = t;
    }
    if (tid >= 64 && tid < 136) {
        int j = tid - 64;
        int ic = j / 36, off = j % 36;
        s[66 + ic][off] = sincos_sum(isc[((size_t)b * 2 + ic) * 36 + off]);
    }
    __syncthreads();

    // vectorized: 8 consecutive k per thread -> short8 store (16B, coalesced)
    for (int i = tid; i < 4 * (KD / 8); i += 256) {
        int q = i / (KD / 8), j8 = i % (KD / 8);
        int gm = q * BN + b;
        if (gm < m0g || gm >= m0g + CM) continue;
        int kbase = j8 * 8;
        short8 pack;
        #pragma unroll
        for (int u = 0; u < 8; u++) {
            int k = kbase + u;
            float v = 0.f;
            if (k < KTRUE) {
                int pi = k / 68, ic = k % 68;
                int r = (q >> 1) + pi / 5;       // (6-WS)=1
                int c = (q & 1) + pi % 5;
                v = s[ic][r * 6 + c];
            }
            bf16 bv = f2b(v);
            pack[u] = *reinterpret_cast<short*>(&bv);
        }
        *reinterpret_cast<short8*>(&Z[(size_t)(gm - m0g) * KD + kbase]) = pack;
    }
}

// ---------------- megabuild: all weights/bias/const-cols in ONE kernel -----------
template<int WSv>
__device__ __forceinline__ bf16 conv_elem(const float* __restrict__ src, int n, int k)
{
    constexpr int KTRUE = 68 * WSv * WSv;
    float v = 0.f;
    if (n < KTRUE && k < KTRUE) {
        int po = n / 68, oc = n % 68, ro = po / WSv, co = po % WSv;
        int pi = k / 68, ic = k % 68, ri = pi / WSv, ci = pi % WSv;
        int kr = ri - ro + 1, kc = ci - co + 1;
        if (kr >= 0 && kr < 3 && kc >= 0 && kc < 3)
            v = src[((oc * 68 + ic) * 3 + kr) * 3 + kc];
    }
    return f2b(v);
}
template<int WSv>
__device__ __forceinline__ bf16 lin_elem(const float* __restrict__ wl, int n, int k)
{
    constexpr int KTRUE = 68 * WSv * WSv;
    float v = 0.f;
    if (n < 576 && k < KTRUE) {
        int pi = k / 68, ic = k % 68;
        v = wl[(size_t)n * KTRUE + ic * (WSv * WSv) + pi];  // ref k-order = ic*ws^2+pi
    }
    return f2b(v);
}

__global__ void megabuild(const float* __restrict__ c1w, const float* __restrict__ c3w,
                          const float* __restrict__ l5w, const float* __restrict__ l4w,
                          const float* __restrict__ l3w, const float* __restrict__ fw,
                          const float* __restrict__ c1b, const float* __restrict__ c3b,
                          const float* __restrict__ bl5, const float* __restrict__ bl4,
                          const float* __restrict__ bl3, const float* __restrict__ bfin,
                          const float* __restrict__ cell, const float* __restrict__ isc,
                          bf16* __restrict__ w1d5, bf16* __restrict__ w3d5,
                          bf16* __restrict__ w1d4, bf16* __restrict__ w3d4,
                          bf16* __restrict__ w1d3, bf16* __restrict__ w3d3,
                          bf16* __restrict__ wl5p, bf16* __restrict__ wl4p,
                          bf16* __restrict__ wl3p, bf16* __restrict__ wfp,
                          float* __restrict__ bias,
                          bf16* __restrict__ Z4, bf16* __restrict__ Z3)
{
    constexpr unsigned S0 = 2u*1792*1728, S1 = 2u*1152*1088, S2 = 2u*640*640;
    constexpr unsigned S3 = 640u*1728, S4 = 640u*1088, S5 = 640u*640;
    constexpr unsigned S6 = 128u*576, S7 = 9216;
    constexpr unsigned S8 = 4u*8192*16*4, S9 = 4u*8192*9*4, S10 = 32768u*28;
    constexpr unsigned O1=S0, O2=O1+S1, O3=O2+S2, O4=O3+S3, O5=O4+S4, O6=O5+S5,
                       O7=O6+S6, O8=O7+S7, O9=O8+S8, O10=O9+S9, OT=O10+S10;
    unsigned e = blockIdx.x * 256u + threadIdx.x;
    if (e >= OT) return;
    if (e < O1) {
        constexpr unsigned per = 1792u*1728;
        unsigned i = (e < per) ? e : e - per;
        bf16* dst = (e < per) ? w1d5 : w3d5;
        const float* src = (e < per) ? c1w : c3w;
        dst[i] = conv_elem<5>(src, (int)(i / 1728u), (int)(i % 1728u));
    } else if (e < O2) {
        unsigned i0 = e - O1; constexpr unsigned per = 1152u*1088;
        unsigned i = (i0 < per) ? i0 : i0 - per;
        bf16* dst = (i0 < per) ? w1d4 : w3d4;
        const float* src = (i0 < per) ? c1w : c3w;
        dst[i] = conv_elem<4>(src, (int)(i / 1088u), (int)(i % 1088u));
    } else if (e < O3) {
        unsigned i0 = e - O2; constexpr unsigned per = 640u*640;
        unsigned i = (i0 < per) ? i0 : i0 - per;
        bf16* dst = (i0 < per) ? w1d3 : w3d3;
        const float* src = (i0 < per) ? c1w : c3w;
        dst[i] = conv_elem<3>(src, (int)(i / 640u), (int)(i % 640u));
    } else if (e < O4) {
        unsigned i = e - O3;
        wl5p[i] = lin_elem<5>(l5w, (int)(i / 1728u), (int)(i % 1728u));
    } else if (e < O5) {
        unsigned i = e - O4;
        wl4p[i] = lin_elem<4>(l4w, (int)(i / 1088u), (int)(i % 1088u));
    } else if (e < O6) {
        unsigned i = e - O5;
        wl3p[i] = lin_elem<3>(l3w, (int)(i / 640u), (int)(i % 640u));
    } else if (e < O7) {
        unsigned i = e - O6, n = i / 576u, k = i % 576u;
        wfp[i] = (n < 64u) ? f2b(fw[n * 576u + k]) : f2b(0.f);
    } else if (e < O8) {
        int i = (int)(e - O7);
        float v = 0.f;
        if (i < 1792)      { int n = i;        if (n < 1700) v = c1b[n % 68]; }
        else if (i < 3584) { int n = i - 1792; if (n < 1700) v = c3b[n % 68]; }
        else if (i < 4736) { int n = i - 3584; if (n < 1088) v = c1b[n % 68]; }
        else if (i < 5888) { int n = i - 4736; if (n < 1088) v = c3b[n % 68]; }
        else if (i < 6528) { int n = i - 5888; if (n < 612)  v = c1b[n % 68]; }
        else if (i < 7168) { int n = i - 6528; if (n < 612)  v = c3b[n % 68]; }
        else if (i < 7808) { int n = i - 7168; if (n < 576)  v = bl5[n]; }
        else if (i < 8448) { int n = i - 7808; if (n < 576)  v = bl4[n]; }
        else if (i < 9088) { int n = i - 8448; if (n < 576)  v = bl3[n]; }
        else               { int n = i - 9088; if (n < 64)   v = bfin[n]; }
        bias[i] = v;
    } else if (e < O9) {
        // Z4 const cols (cell/isc), ic = 64..67
        unsigned i = e - O8;
        int j = (int)(i & 3u); i >>= 2;
        int pi = (int)(i & 15u); i >>= 4;
        int b = (int)(i & 8191u); int q = (int)(i >> 13);
        float t;
        if (j < 2) t = cell[b * 2 + j];
        else {
            int r = (q >> 1) * 2 + pi / 4, c = (q & 1) * 2 + pi % 4;
            t = isc[((size_t)b * 2 + (j - 2)) * 36 + r * 6 + c];
        }
        Z4[((size_t)q * BN + b) * 1088 + pi * 68 + 64 + j] = f2b(sincos_sum(t));
    } else if (e < O10) {
        // Z3 const cols
        unsigned i = e - O9;
        int j = (int)(i & 3u); i >>= 2;
        int pi = (int)(i % 9u); i /= 9u;
        int b = (int)(i & 8191u); int q = (int)(i >> 13);
        float t;
        if (j < 2) t = cell[b * 2 + j];
        else {
            int r = (q >> 1) * 3 + pi / 3, c = (q & 1) * 3 + pi % 3;
            t = isc[((size_t)b * 2 + (j - 2)) * 36 + r * 6 + c];
        }
        Z3[((size_t)q * BN + b) * 640 + pi * 68 + 64 + j] = f2b(sincos_sum(t));
    } else {
        // Z3 pad cols 612..639 = 0 (avoid NaN-poison from workspace)
        unsigned i = e - O10;
        int m = (int)(i / 28u), t = (int)(i % 28u);
        Z3[(size_t)m * 640 + 612 + t] = f2b(0.f);
    }
}

// ---------------- async global->LDS, 16B per lane (m97 idiom) --------------------
__device__ __forceinline__ void gload_lds16(const bf16* g, const bf16* lds_wave_base)
{
    unsigned off = (unsigned)(uintptr_t)lds_wave_base;
    off = __builtin_amdgcn_readfirstlane(off);
    __builtin_amdgcn_global_load_lds((const __attribute__((address_space(1))) unsigned int*)g,
                                     (__attribute__((address_space(3))) unsigned int*)off,
                                     16, 0, 0);
}

__device__ __forceinline__ int imin(int a, int b) { return a < b ? a : b; }
__device__ __forceinline__ int imax(int a, int b) { return a > b ? a : b; }

// =============================================================================
// gemm8 (r8 kernel, UNCHANGED — verified): panel-major tile order, r5 pipeline
// core, counted vmcnt(3), conflict-free swizzle, setprio.
//   WIDE=0: BM=256, BN=128 ; WIDE=1: BM=128, BN=256.
// r9 change is LAUNCHER-ONLY: the GEMM chain is executed in M-chunks of 8192
// rows (pointer offsets). Producer writes leave dirty lines in the producing
// XCD's L2; the XCD-affine m-partition maps the consumer of those rows to the
// SAME XCD; a chunk's operand share (3.5/2.2/1.3 MB per XCD for KD=1728/1088/
// 640) fits the 4 MB XCD L2 -> intermediate reads become L2-sourced instead of
// L3-sourced (measured staging ceiling 21 B/cy/CU = L3 BW).
// EPI: 0 bias+relu+sincos->C ; 1 bias+relu->C ;
//      2 bias+relu+sincos -> scatter into Z_next (window WN)
// =============================================================================
template<int EPI, int WS, int WN, int WIDE>
__global__ __launch_bounds__(512, 4)
void gemm8(const bf16* __restrict__ A, const bf16* __restrict__ Bm, int KD,
           const float* __restrict__ bias, int ntiles, int mtiles,
           bf16* __restrict__ C, int ldc, int nlimit,
           int m0g, bf16* __restrict__ znext)
{
    constexpr int BMc = WIDE ? 128 : 256;
    constexpr int BNc = WIDE ? 256 : 128;
    constexpr int NWN = WIDE ? 4 : 2;            // waves along N
    __shared__ bf16 As[3][BMc * 32];
    __shared__ bf16 Bs[3][BNc * 32];
    const int tid = threadIdx.x;
    const int wave = tid >> 6, lane = tid & 63;
    const int l15 = lane & 15, lq = lane >> 4;
    const int wr = (wave / NWN) * 64, wc = (wave % NWN) * 64;

    // ---- panel-major tile mapping (grid = ntiles * mtiles, mtiles % 8 == 0) ----
    const int xcd = blockIdx.x & 7, local = blockIdx.x >> 3;
    const int mloc = mtiles >> 3;                // m-tiles per XCD
    const int PP = (mloc >= 4) ? 4 : mloc;       // panel size (divides mloc)
    const int grp = ntiles * PP;
    const int p = local / grp, rem = local % grp;
    const int n_idx = rem / PP, mi = rem % PP;
    const int m_idx = xcd * mloc + p * PP + mi;
    const int n0 = n_idx * BNc, m0 = m_idx * BMc;

    // ---- K-banding spans (32-aligned) ----
    int s0b = 0, s0e = KD, s1b = 0, s1e = 0, s2b = 0, s2e = 0;
    if (WS > 0) {
        int po_lo = imin(n0 / 68, WS * WS - 1);
        int po_hi = imin((n0 + BNc - 1) / 68, WS * WS - 1);
        int ro_lo = po_lo / WS, ro_hi = po_hi / WS;
        int r_lo = imax(ro_lo - 1, 0), r_hi = imin(ro_hi + 1, WS - 1);
        int ci_lo = 0, ci_hi = WS - 1;
        if (ro_lo == ro_hi) {
            ci_lo = imax(po_lo % WS - 1, 0);
            ci_hi = imin(po_hi % WS + 1, WS - 1);
        }
        if (ci_lo == 0 && ci_hi == WS - 1) {
            s0b = (r_lo * WS * 68) & ~31;
            s0e = imin(KD, ((r_hi + 1) * WS * 68 + 31) & ~31);
        } else {
            s0b = ((r_lo * WS + ci_lo) * 68) & ~31;
            s0e = imin(KD, (((r_lo * WS + ci_hi + 1) * 68) + 31) & ~31);
            if (r_hi > r_lo) {
                s1b = (((r_lo + 1) * WS + ci_lo) * 68) & ~31;
                s1e = imin(KD, ((((r_lo + 1) * WS + ci_hi + 1) * 68) + 31) & ~31);
            }
            if (r_hi > r_lo + 1) {
                s2b = (((r_lo + 2) * WS + ci_lo) * 68) & ~31;
                s2e = imin(KD, ((((r_lo + 2) * WS + ci_hi + 1) * 68) + 31) & ~31);
            }
        }
    }
    const int c0 = (s0e - s0b) >> 5;
    const int c1 = c0 + ((s1e - s1b) >> 5);
    const int nt = c1 + ((s2e - s2b) >> 5);
    auto k0_of = [&](int t2) -> int {
        int k = s0b + (t2 << 5);
        if (t2 >= c0) k = s1b + ((t2 - c0) << 5);
        if (t2 >= c1) k = s2b + ((t2 - c1) << 5);
        return k;
    };

    // ---- staging addressing: linear LDS dest, pre-swizzled global source ----
    const int srow = tid >> 2;
    const int scx = (tid & 3) ^ ((srow >> 1) & 3);
    const int sOff = srow * 32 + (tid & 3) * 8;
    // fragment read swizzle: row = 16-aligned + l15 -> (row>>1)&3 = (l15>>1)&3
    const int swz = (lq ^ ((l15 >> 1) & 3)) * 8;
    const int offA0 = (wr + l15) * 32 + swz;     // + i*512
    const int offB0 = (wc + l15) * 32 + swz;     // + j*512

    const bf16* aSrc = A + (size_t)(m0 + srow) * KD + scx * 8;
    const bf16* bSrc = Bm + (size_t)(n0 + srow) * KD + scx * 8;

    auto stageAll = [&](int k0, int buf) {   // 3 loads total
        if (WIDE) {
            gload_lds16(aSrc + k0, &As[buf][sOff]);
            gload_lds16(bSrc + k0, &Bs[buf][sOff]);
            gload_lds16(bSrc + k0 + (size_t)128 * KD, &Bs[buf][sOff + 4096]);
        } else {
            gload_lds16(aSrc + k0, &As[buf][sOff]);
            gload_lds16(aSrc + k0 + (size_t)128 * KD, &As[buf][sOff + 4096]);
            gload_lds16(bSrc + k0, &Bs[buf][sOff]);
        }
    };

    f32x4 acc[4][4];
    #pragma unroll
    for (int i = 0; i < 4; i++)
        #pragma unroll
        for (int j = 0; j < 4; j++) { f32x4 z = {0.f, 0.f, 0.f, 0.f}; acc[i][j] = z; }

    // ---- prologue: stage tiles 0,1; full drain ----
    {
        stageAll(k0_of(0), 0);
        if (nt > 1) stageAll(k0_of(1), 1);
        __syncthreads();
    }

    // ---- main loop: one barrier per K-tile (r3-r5 verified ledger) ----
    for (int t = 0; t < nt; ++t) {
        const int cur = t % 3;
        const int nx = (t + 2) % 3;
        const bool pf = (t + 2) < nt;

        const bf16* Ac = &As[cur][0];
        const bf16* Bc = &Bs[cur][0];

        short8 af[4], bg[4];
        #pragma unroll
        for (int i = 0; i < 4; i++) af[i] = *(const short8*)&Ac[offA0 + i * 512];
        #pragma unroll
        for (int j = 0; j < 4; j++) bg[j] = *(const short8*)&Bc[offB0 + j * 512];

        if (pf) stageAll(k0_of(t + 2), nx);

        __builtin_amdgcn_s_setprio(1);
        #pragma unroll
        for (int i = 0; i < 4; i++)
            #pragma unroll
            for (int j = 0; j < 4; j++)
                acc[i][j] = __builtin_amdgcn_mfma_f32_16x16x32_bf16(af[i], bg[j], acc[i][j], 0, 0, 0);
        __builtin_amdgcn_s_setprio(0);

        if (pf) asm volatile("s_waitcnt vmcnt(3)" ::: "memory");
        else    asm volatile("s_waitcnt vmcnt(0)" ::: "memory");
        __builtin_amdgcn_s_barrier();
    }

    // ---- epilogue (scalar, r5-verified) ----
    float bj[4];
    #pragma unroll
    for (int j = 0; j < 4; j++) bj[j] = bias[n0 + wc + j * 16 + l15];

    #pragma unroll
    for (int i = 0; i < 4; i++) {
        #pragma unroll
        for (int j = 0; j < 4; j++) {
            int n = n0 + wc + j * 16 + l15;
            #pragma unroll
            for (int r = 0; r < 4; r++) {
                int m = m0 + wr + i * 16 + lq * 4 + r;
                float v = acc[i][j][r];
                if (EPI == 0) {
                    if (n < nlimit) {
                        v += bj[j]; v = fmaxf(v, 0.f); v = sincos_sum(v);
                        C[(size_t)m * ldc + n] = f2b(v);
                    }
                } else if (EPI == 1) {
                    if (n < nlimit) {
                        v += bj[j]; v = fmaxf(v, 0.f);
                        C[(size_t)m * ldc + n] = f2b(v);
                    }
                } else {
                    if (n < 576) {
                        v += bj[j]; v = fmaxf(v, 0.f);
                        bf16 tv = f2b(sincos_sum(v));
                        int gm = m0g + m;
                        int q = gm >> 13, b = gm & (BN - 1);
                        int ch = n / 9, p2 = n % 9;
                        int R = p2 / 3 + (q >> 1) * 3, Cc = p2 % 3 + (q & 1) * 3;
                        constexpr int OFF = 6 - WN;
                        constexpr int KDN = (WN == 4) ? 1088 : 640;
                        #pragma unroll
                        for (int qr = 0; qr < 2; qr++) {
                            int rr = R - OFF * qr;
                            if (rr < 0 || rr >= WN) continue;
                            #pragma unroll
                            for (int qc = 0; qc < 2; qc++) {
                                int cc = Cc - OFF * qc;
                                if (cc < 0 || cc >= WN) continue;
                                int pi = rr * WN + cc;
                                znext[((size_t)((qr * 2 + qc) * BN + b)) * KDN + pi * 68 + ch] = tv;
                            }
                        }
                    }
                }
            }
        }
    }
}

// ---------------- old 128x128 kernel (verified) — final tiny GEMM ---------------
template<int EPI, int WS, int WN>
__global__ __launch_bounds__(256)
void gemm_bt(const bf16* __restrict__ A, const bf16* __restrict__ Bm, int KD,
             const float* __restrict__ bias, int ntiles,
             bf16* __restrict__ C, int ldc, int nlimit,
             int m0g, bf16* __restrict__ znext,
             const bf16* __restrict__ afin_xc, float* __restrict__ outp)
{
    __shared__ bf16 As[128 * 32];
    __shared__ bf16 Bs[128 * 32];
    const int tid = threadIdx.x;
    const int wave = tid >> 6, lane = tid & 63;
    const int l15 = lane & 15, lq = lane >> 4;
    const int wr = (wave >> 1) * 64, wc = (wave & 1) * 64;

    const int id = blockIdx.x;
    const int mt8 = (int)gridDim.x / (ntiles * 8);   // m-tiles per XCD
    const int xcd = id & 7, local = id >> 3;
    const int m_idx = xcd * mt8 + local / ntiles;
    const int n_idx = local % ntiles;
    const int n0 = n_idx * 128, m0 = m_idx * 128;

    int nspans = 1, sbeg[4], send[4];
    sbeg[0] = 0; send[0] = KD;
    if (WS > 0) {
        int po_lo = imin(n0 / 68, WS * WS - 1);
        int po_hi = imin((n0 + 127) / 68, WS * WS - 1);
        int ro_lo = po_lo / WS, ro_hi = po_hi / WS;
        int r_lo = imax(ro_lo - 1, 0), r_hi = imin(ro_hi + 1, WS - 1);
        int ci_lo = 0, ci_hi = WS - 1;
        if (ro_lo == ro_hi) {
            ci_lo = imax(po_lo % WS - 1, 0);
            ci_hi = imin(po_hi % WS + 1, WS - 1);
        }
        if (ci_lo == 0 && ci_hi == WS - 1) {
            sbeg[0] = (r_lo * WS * 68) & ~31;
            send[0] = imin(KD, ((r_hi + 1) * WS * 68 + 31) & ~31);
        } else {
            nspans = 0;
            for (int ri = r_lo; ri <= r_hi; ri++) {
                sbeg[nspans] = ((ri * WS + ci_lo) * 68) & ~31;
                send[nspans] = imin(KD, (((ri * WS + ci_hi + 1) * 68) + 31) & ~31);
                nspans++;
            }
        }
    }

    float bj[4];
    #pragma unroll
    for (int j = 0; j < 4; j++) bj[j] = bias[n0 + wc + j * 16 + l15];

    const bf16* Ab = A + (size_t)m0 * KD;
    const bf16* Bb = Bm + (size_t)n0 * KD;
    const int srow = tid >> 2, scol = (tid & 3) * 8;
    const bf16* aG0 = Ab + (size_t)srow * KD + scol;
    const bf16* aG1 = Ab + (size_t)(srow + 64) * KD + scol;
    const bf16* bG0 = Bb + (size_t)srow * KD + scol;
    const bf16* bG1 = Bb + (size_t)(srow + 64) * KD + scol;
    const bf16* lA0 = &As[wave * 512];
    const bf16* lA1 = &As[2048 + wave * 512];
    const bf16* lB0 = &Bs[wave * 512];
    const bf16* lB1 = &Bs[2048 + wave * 512];

    f32x4 acc[4][4];
    #pragma unroll
    for (int i = 0; i < 4; i++)
        #pragma unroll
        for (int j = 0; j < 4; j++) { f32x4 z = {0.f, 0.f, 0.f, 0.f}; acc[i][j] = z; }

    for (int s = 0; s < nspans; s++) {
        for (int k0 = sbeg[s]; k0 < send[s]; k0 += 32) {
            gload_lds16(aG0 + k0, lA0);
            gload_lds16(aG1 + k0, lA1);
            gload_lds16(bG0 + k0, lB0);
            gload_lds16(bG1 + k0, lB1);
            __syncthreads();
            short8 af[4], bg[4];
            #pragma unroll
            for (int i = 0; i < 4; i++) af[i] = *(const short8*)&As[(wr + i * 16 + l15) * 32 + lq * 8];
            #pragma unroll
            for (int j = 0; j < 4; j++) bg[j] = *(const short8*)&Bs[(wc + j * 16 + l15) * 32 + lq * 8];
            #pragma unroll
            for (int i = 0; i < 4; i++)
                #pragma unroll
                for (int j = 0; j < 4; j++)
                    acc[i][j] = __builtin_amdgcn_mfma_f32_16x16x32_bf16(af[i], bg[j], acc[i][j], 0, 0, 0);
            __syncthreads();
        }
    }

    #pragma unroll
    for (int i = 0; i < 4; i++) {
        #pragma unroll
        for (int j = 0; j < 4; j++) {
            int n = n0 + wc + j * 16 + l15;
            #pragma unroll
            for (int r = 0; r < 4; r++) {
                int m = m0 + wr + i * 16 + lq * 4 + r;
                float v = acc[i][j][r];
                if (EPI == 0) {
                    if (n < nlimit) {
                        v += bj[j]; v = fmaxf(v, 0.f); v = sincos_sum(v);
                        C[(size_t)m * ldc + n] = f2b(v);
                    }
                } else if (EPI == 1) {
                    if (n < nlimit) {
                        v += bj[j]; v = fmaxf(v, 0.f);
                        C[(size_t)m * ldc + n] = f2b(v);
                    }
                } else if (EPI == 2) {
                    if (n < 576) {
                        v += bj[j]; v = fmaxf(v, 0.f);
                        bf16 t = f2b(sincos_sum(v));
                        int gm = m0g + m;
                        int q = gm >> 13, b = gm & (BN - 1);
                        int ch = n / 9, p = n % 9;
                        int R = p / 3 + (q >> 1) * 3, Cc = p % 3 + (q & 1) * 3;
                        constexpr int OFF = 6 - WN;
                        constexpr int KDN = (WN == 4) ? 1088 : 640;
                        #pragma unroll
                        for (int qr = 0; qr < 2; qr++) {
                            int rr = R - OFF * qr;
                            if (rr < 0 || rr >= WN) continue;
                            #pragma unroll
                            for (int qc = 0; qc < 2; qc++) {
                                int cc = Cc - OFF * qc;
                                if (cc < 0 || cc >= WN) continue;
                                int pi = rr * WN + cc;
                                znext[((size_t)((qr * 2 + qc) * BN + b)) * KDN + pi * 68 + ch] = t;
                            }
                        }
                    }
                } else {
                    if (n < 64) {
                        v += bj[j];
                        int gm = m0g + m;
                        int f = gm * 64 + n;        // c-flat == out-flat
                        int b2 = f >> 8, rem = f & 255;
                        int ch2 = rem >> 2, ii = (rem >> 1) & 1, jj = rem & 1;
                        int qq = ii * 2 + jj;
                        const int offt[4] = {8, 6, 2, 0};
                        float xc = b2f(afin_xc[((size_t)qq * BN + b2) * 576 + ch2 * 9 + offt[qq]]);
                        outp[f] = v * xc;
                    }
                }
            }
        }
    }
}

extern "C" void kernel_launch(void* const* d_in, const int* in_sizes, int n_in,
                              void* d_out, int out_size, void* d_ws, size_t ws_size,
                              hipStream_t stream)
{
    const float* x    = (const float*)d_in[0];
    const float* cell = (const float*)d_in[1];
    const float* isc  = (const float*)d_in[2];
    const float* c1w  = (const float*)d_in[3];
    const float* c1b  = (const float*)d_in[4];
    const float* c3w  = (const float*)d_in[5];
    const float* c3b  = (const float*)d_in[6];
    const float* l5w  = (const float*)d_in[7];
    const float* l5b  = (const float*)d_in[8];
    const float* l4w  = (const float*)d_in[9];
    const float* l4b  = (const float*)d_in[10];
    const float* l3w  = (const float*)d_in[11];
    const float* l3b  = (const float*)d_in[12];
    const float* fw   = (const float*)d_in[13];
    const float* fb   = (const float*)d_in[14];

    char* base = (char*)d_ws;
    size_t cur = 0;
    auto take = [&](size_t bytes) -> char* {
        char* r = base + cur; cur += (bytes + 255) & ~(size_t)255; return r;
    };

    const size_t Z4B = (size_t)MTOT * 1088 * 2;   // 71.3 MB
    const size_t Z3B = (size_t)MTOT * 640 * 2;    // 41.9 MB
    const size_t AFB = (size_t)MTOT * 576 * 2;    // 37.7 MB
    size_t wbytes = 2 * (1792ull * 1728 + 1152ull * 1088 + 640ull * 640) * 2
                  + (640ull * 1728 + 640ull * 1088 + 640ull * 640) * 2
                  + 128ull * 576 * 2 + 9216ull * 4 + 64 * 256;
    auto need = [&](int nc) -> size_t {
        return Z4B + Z3B + AFB + wbytes + 2 * ((size_t)(MTOT / nc) * 1728 * 2);
    };
    int nchunk = (ws_size >= need(1)) ? 1 : (ws_size >= need(2)) ? 2
               : (ws_size >= need(4)) ? 4 : (ws_size >= need(8)) ? 8 : 16;

    bf16* Z4   = (bf16*)take(Z4B);
    bf16* Z3   = (bf16*)take(Z3B);
    bf16* afinb = (bf16*)take(AFB);
    bf16* w1d5 = (bf16*)take(1792ull * 1728 * 2);
    bf16* w3d5 = (bf16*)take(1792ull * 1728 * 2);
    bf16* w1d4 = (bf16*)take(1152ull * 1088 * 2);
    bf16* w3d4 = (bf16*)take(1152ull * 1088 * 2);
    bf16* w1d3 = (bf16*)take(640ull * 640 * 2);
    bf16* w3d3 = (bf16*)take(640ull * 640 * 2);
    bf16* wl5p = (bf16*)take(640ull * 1728 * 2);
    bf16* wl4p = (bf16*)take(640ull * 1088 * 2);
    bf16* wl3p = (bf16*)take(640ull * 640 * 2);
    bf16* wfp  = (bf16*)take(128ull * 576 * 2);
    float* biasb = (float*)take(9216ull * 4);
    int CM = MTOT / nchunk;
    int mt = CM / 128;
    int mt2 = CM / 256;
    bf16* Za = (bf16*)take((size_t)CM * 1728 * 2);
    bf16* Zb = (bf16*)take((size_t)CM * 1728 * 2);

    // -------- stage 0: all weight repacks, bias, Z4/Z3 const cols, Z3 pad --------
    {
        constexpr unsigned OT = 2u*1792*1728 + 2u*1152*1088 + 2u*640*640
                              + 640u*1728 + 640u*1088 + 640u*640 + 128u*576 + 9216
                              + 4u*8192*16*4 + 4u*8192*9*4 + 32768u*28;
        megabuild<<<(OT + 255) / 256, 256, 0, stream>>>(
            c1w, c3w, l5w, l4w, l3w, fw, c1b, c3b, l5b, l4b, l3b, fb, cell, isc,
            w1d5, w3d5, w1d4, w3d4, w1d3, w3d3, wl5p, wl4p, wl3p, wfp, biasb, Z4, Z3);
    }

    if (nchunk == 1) {
        // ===== r9 path: full-size Za/Zb, zprep ONCE, chain chunked at SM=8192 =====
        // Per chunk cc: rows [cc*SM, (cc+1)*SM). XCD-affine m-partition keeps a
        // chunk's rows on fixed XCDs; producer's dirty L2 lines feed the consumer.
        constexpr int SM = 8192;
        constexpr int NC = MTOT / SM;           // 4
        const int smt = SM / 128;               // 64  (WIDE m-tiles / chunk)
        const int smt2 = SM / 256;              // 32  (narrow m-tiles / chunk)

        zprep_block<<<BN, 256, 0, stream>>>(x, cell, isc, Za, 0, MTOT);

        for (int cc = 0; cc < NC; cc++) {
            size_t o5 = (size_t)cc * SM * 1728;
            gemm8<0, 5, 0, 1><<<7 * smt, 512, 0, stream>>>(Za + o5, w1d5, 1728, biasb + 0,
                                                           7, smt, Zb + o5, 1728, 1728,
                                                           0, nullptr);
            gemm8<1, 5, 0, 1><<<7 * smt, 512, 0, stream>>>(Zb + o5, w3d5, 1728, biasb + 1792,
                                                           7, smt, Za + o5, 1728, 1728,
                                                           0, nullptr);
            gemm8<2, 0, 4, 0><<<5 * smt2, 512, 0, stream>>>(Za + o5, wl5p, 1728, biasb + 7168,
                                                            5, smt2, nullptr, 0, 0,
                                                            cc * SM, Z4);
        }
        for (int cc = 0; cc < NC; cc++) {
            size_t o4 = (size_t)cc * SM * 1088;
            gemm8<0, 4, 0, 0><<<9 * smt2, 512, 0, stream>>>(Z4 + o4, w1d4, 1088, biasb + 3584,
                                                            9, smt2, (bf16*)((char*)Zb) + o4,
                                                            1088, 1088, 0, nullptr);
            gemm8<1, 4, 0, 0><<<9 * smt2, 512, 0, stream>>>(Zb + o4, w3d4, 1088, biasb + 4736,
                                                            9, smt2, Za + o4, 1088, 1088,
                                                            0, nullptr);
            gemm8<2, 0, 3, 0><<<5 * smt2, 512, 0, stream>>>(Za + o4, wl4p, 1088, biasb + 7808,
                                                            5, smt2, nullptr, 0, 0,
                                                            cc * SM, Z3);
        }
        for (int cc = 0; cc < NC; cc++) {
            size_t o3 = (size_t)cc * SM * 640;
            gemm8<0, 3, 0, 0><<<5 * smt2, 512, 0, stream>>>(Z3 + o3, w1d3, 640, biasb + 5888,
                                                            5, smt2, Zb + o3, 640, 640,
                                                            0, nullptr);
            gemm8<1, 3, 0, 0><<<5 * smt2, 512, 0, stream>>>(Zb + o3, w3d3, 640, biasb + 6528,
                                                            5, smt2, Za + o3, 640, 640,
                                                            0, nullptr);
            gemm8<1, 0, 0, 0><<<5 * smt2, 512, 0, stream>>>(Za + o3, wl3p, 640, biasb + 8448,
                                                            5, smt2,
                                                            afinb + (size_t)cc * SM * 576,
                                                            576, 576, 0, nullptr);
        }
        gemm_bt<3, 0, 0><<<mt, 256, 0, stream>>>(afinb, wfp, 576, biasb + 9088, 1,
                                                 nullptr, 0, 0, 0, nullptr, afinb,
                                                 (float*)d_out);
    } else {
        // ===== fallback: r8 path with per-chunk buffers (small workspace) =====
        for (int c = 0; c < nchunk; c++) {
            int m0g = c * CM;
            zprep_block<<<BN, 256, 0, stream>>>(x, cell, isc, Za, m0g, CM);
            gemm8<0, 5, 0, 1><<<7 * mt, 512, 0, stream>>>(Za, w1d5, 1728, biasb + 0, 7, mt,
                                                          Zb, 1728, 1728, 0, nullptr);
            gemm8<1, 5, 0, 1><<<7 * mt, 512, 0, stream>>>(Zb, w3d5, 1728, biasb + 1792, 7, mt,
                                                          Za, 1728, 1728, 0, nullptr);
            gemm8<2, 0, 4, 0><<<5 * mt2, 512, 0, stream>>>(Za, wl5p, 1728, biasb + 7168, 5, mt2,
                                                           nullptr, 0, 0, m0g, Z4);
        }
        for (int c = 0; c < nchunk; c++) {
            int m0g = c * CM;
            gemm8<0, 4, 0, 0><<<9 * mt2, 512, 0, stream>>>(Z4 + (size_t)m0g * 1088, w1d4, 1088,
                                                           biasb + 3584, 9, mt2, Zb, 1088, 1088,
                                                           0, nullptr);
            gemm8<1, 4, 0, 0><<<9 * mt2, 512, 0, stream>>>(Zb, w3d4, 1088, biasb + 4736, 9, mt2,
                                                           Za, 1088, 1088, 0, nullptr);
            gemm8<2, 0, 3, 0><<<5 * mt2, 512, 0, stream>>>(Za, wl4p, 1088, biasb + 7808, 5, mt2,
                                                           nullptr, 0, 0, m0g, Z3);
        }
        for (int c = 0; c < nchunk; c++) {
            int m0g = c * CM;
            gemm8<0, 3, 0, 0><<<5 * mt2, 512, 0, stream>>>(Z3 + (size_t)m0g * 640, w1d3, 640,
                                                           biasb + 5888, 5, mt2, Zb, 640, 640,
                                                           0, nullptr);
            gemm8<1, 3, 0, 0><<<5 * mt2, 512, 0, stream>>>(Zb, w3d3, 640, biasb + 6528, 5, mt2,
                                                           Za, 640, 640, 0, nullptr);
            gemm8<1, 0, 0, 0><<<5 * mt2, 512, 0, stream>>>(Za, wl3p, 640, biasb + 8448, 5, mt2,
                                                           afinb + (size_t)m0g * 576, 576, 576,
                                                           0, nullptr);
        }
        for (int c = 0; c < nchunk; c++) {
            int m0g = c * CM;
            gemm_bt<3, 0, 0><<<mt, 256, 0, stream>>>(afinb + (size_t)m0g * 576, wfp, 576,
                                                     biasb + 9088, 1, nullptr, 0, 0, m0g,
                                                     nullptr, afinb, (float*)d_out);
        }
    }
}